// Round 17
// baseline (229.791 us; speedup 1.0000x reference)
//
#include <hip/hip_runtime.h>
#include <stdint.h>

typedef unsigned short u16;
typedef float f32x4 __attribute__((ext_vector_type(4)));
typedef __bf16 bf16x8 __attribute__((ext_vector_type(8)));
typedef unsigned short u16x8 __attribute__((ext_vector_type(8)));
typedef unsigned short u16x4 __attribute__((ext_vector_type(4)));

#define N1P 6400   // padded concat width: q(1024)|k(1024)|v(2048)|b(16)|a(16)|g(2048)|pad(224)

__device__ __forceinline__ u16 f2bf(float f) {
    union { float f; uint32_t u; } v; v.f = f;
    uint32_t u = v.u;
    return (u16)((u + 0x7FFFu + ((u >> 16) & 1u)) >> 16);
}
__device__ __forceinline__ float bf2f(u16 h) {
    union { uint32_t u; float f; } v; v.u = ((uint32_t)h) << 16; return v.f;
}
__device__ __forceinline__ float sigm(float x) { return 1.f / (1.f + __expf(-x)); }

__device__ __forceinline__ void async16(const u16* g, u16* l) {
    __builtin_amdgcn_global_load_lds((const __attribute__((address_space(1))) void*)g,
                                     (__attribute__((address_space(3))) void*)l, 16, 0, 0);
}

// byte offset inside a [R][64] bf16 "swizzled image": 16B units XOR'd with row&7
__device__ __forceinline__ int swz64(int row, int col) {
    return row * 128 + ((((col >> 3) ^ (row & 7)) << 3) + (col & 7)) * 2;
}
// MFMA fragment read from a swizzled [R][64] bf16 image (rows rowbase..rowbase+15, K-offset kk*32)
__device__ __forceinline__ bf16x8 frag64(const u16* m, int rowbase, int lane, int kk) {
    const int row = rowbase + (lane & 15);
    const int unit = (lane >> 4) + (kk << 2);
    return *(const bf16x8*)((const char*)m + row * 128 + ((unit ^ (row & 7)) << 4));
}

// ---------------- fused transpose + fp32->bf16 convert (10 weights) + rmsnorm-1 (one launch)
// Transpose tile: 64(k) x 32(n); writes one u16x8 per thread.
// mode 0: dst row = rowOff + n*rowStride ; mode 1: dst row = rowOff + (n>>4)*32 + (n&15)
struct TJob { const float* src; u16* dst; int rows, cols, rowOff, rowStride, nOut, blkBase, gx, mode; };
struct TJobs { TJob j[10]; };

__global__ __launch_bounds__(256) void k_transpose_all(TJobs jobs, int njobs, int rmsBase,
                                                       const float* __restrict__ xin,
                                                       const float* __restrict__ n1w,
                                                       u16* __restrict__ hOut) {
    __shared__ float tile[64][33];
    const int bid = blockIdx.x;
    const int tid = threadIdx.x;
    if (bid >= rmsBase) {
        // ---- rmsnorm row (D=1024, fp32 -> bf16)
        const int row = bid - rmsBase;
        const int lane = tid & 63, wave = tid >> 6;
        const float4 v = ((const float4*)(xin + (size_t)row * 1024))[tid];
        float ss = v.x * v.x + v.y * v.y + v.z * v.z + v.w * v.w;
#pragma unroll
        for (int o = 1; o < 64; o <<= 1) ss += __shfl_xor(ss, o);
        float* sred = &tile[0][0];
        if (lane == 0) sred[wave] = ss;
        __syncthreads();
        const float tot = sred[0] + sred[1] + sred[2] + sred[3];
        const float rn = rsqrtf(tot * (1.f / 1024.f) + 1e-6f);
        const float4 wv = ((const float4*)n1w)[tid];
        uint2 pk;
        pk.x = (uint32_t)f2bf(v.x * rn * wv.x) | ((uint32_t)f2bf(v.y * rn * wv.y) << 16);
        pk.y = (uint32_t)f2bf(v.z * rn * wv.z) | ((uint32_t)f2bf(v.w * rn * wv.w) << 16);
        *(uint2*)&hOut[(size_t)row * 1024 + tid * 4] = pk;
        return;
    }
    int ji = 0;
#pragma unroll
    for (int i = 1; i < 10; ++i)
        if (i < njobs && bid >= jobs.j[i].blkBase) ji = i;
    const TJob J = jobs.j[ji];
    const int bx = bid - J.blkBase;
    const int n0 = (bx % J.gx) * 32, k0 = (bx / J.gx) * 64;
    const int tx = tid & 31, ty = tid >> 5;      // 32 x 8
    const int c = n0 + tx;
    const bool cok = (c < J.cols);
#pragma unroll
    for (int i = 0; i < 8; ++i) {
        const int r = k0 + i * 8 + ty;           // rows are multiples of 64 -> always in range
        tile[i * 8 + ty][tx] = cok ? J.src[(size_t)r * J.cols + c] : 0.f;
    }
    __syncthreads();
    const int n = tid >> 3, seg = tid & 7;
    const int ng = n0 + n;
    if (ng < J.nOut) {
        u16x8 o;
#pragma unroll
        for (int e = 0; e < 8; ++e) o[e] = f2bf(tile[seg * 8 + e][n]);
        const int drow = (J.mode == 0) ? (J.rowOff + ng * J.rowStride)
                                       : (J.rowOff + ((ng >> 4) << 5) + (ng & 15));
        *(u16x8*)&J.dst[(size_t)drow * J.rows + k0 + seg * 8] = o;
    }
}

// ---------------- rmsnorm over D=1024, fp32 in -> bf16 out (used for norm-2 only)
__global__ __launch_bounds__(256) void k_rmsnorm(const float* __restrict__ x, const float* __restrict__ w,
                                                 u16* __restrict__ out) {
    const int row = blockIdx.x, tid = threadIdx.x, lane = tid & 63, wave = tid >> 6;
    const float4 v = ((const float4*)(x + (size_t)row * 1024))[tid];
    float ss = v.x * v.x + v.y * v.y + v.z * v.z + v.w * v.w;
#pragma unroll
    for (int o = 1; o < 64; o <<= 1) ss += __shfl_xor(ss, o);
    __shared__ float sred[4];
    if (lane == 0) sred[wave] = ss;
    __syncthreads();
    const float tot = sred[0] + sred[1] + sred[2] + sred[3];
    const float rn = rsqrtf(tot * (1.f / 1024.f) + 1e-6f);
    const float4 wv = ((const float4*)w)[tid];
    uint2 pk;
    pk.x = (uint32_t)f2bf(v.x * rn * wv.x) | ((uint32_t)f2bf(v.y * rn * wv.y) << 16);
    pk.y = (uint32_t)f2bf(v.z * rn * wv.z) | ((uint32_t)f2bf(v.w * rn * wv.w) << 16);
    *(uint2*)&out[(size_t)row * 1024 + tid * 4] = pk;
}

// ---------------- 256x256 8-phase GEMM (T2+T3+T4+T5), BK=64, 8 waves (2Mx4N), wave tile 128x64.
// A[2048][Kd] bf16 row-major, Bt[N'][Kd] bf16 row-major. Kd must be multiple of 128.
// EPI 2 = bf16 store (width N); EPI 3 = fused silu(u1)*u3, B group-16-interleaved (out width N)
template <int EPI>
__global__ __launch_bounds__(512, 2) void k_gemm256(const u16* __restrict__ A, const u16* __restrict__ Bt,
                                                    u16* __restrict__ Cout, int N, int Kd) {
    __shared__ __align__(16) u16 L[65536];   // 128KB: buf{0,1} x (A 256x64 | B 256x64) swizzled images
    const int q8 = (int)gridDim.x >> 3;
    const int bid = blockIdx.x;
    const int wg = (bid & 7) * q8 + (bid >> 3);      // XCD-contiguous
    const int bm = wg & 7, bn = wg >> 3;             // M blocks = 2048/256 = 8
    const int tid = threadIdx.x, lane = tid & 63, wave = tid >> 6;
    const int wm = wave >> 2, wn = wave & 3;         // 2 x 4 wave grid

    const int scol = ((tid & 7) ^ ((tid >> 3) & 7)) * 8;  // pre-swizzled source granule
    const u16* gA = A + (size_t)(bm * 256 + (tid >> 3)) * Kd + scol;
    const u16* gB = Bt + (size_t)(bn * 256 + (tid >> 3)) * Kd + scol;
    u16* dstT = L + tid * 8;

    const int NT = Kd >> 6;
    const int NI = NT >> 1;

    auto issue = [&](const u16* g, int mtx, int kt, int h) {   // one half-tile = 2 gloads/thread
        u16* d = dstT + (kt & 1) * 32768 + mtx * 16384 + h * 8192;
        const u16* s = g + (size_t)(h * 128) * Kd + kt * 64;
        async16(s, d);
        async16(s + (size_t)64 * Kd, d + 4096);
    };

    issue(gB, 1, 0, 0); issue(gB, 1, 0, 1);
    issue(gA, 0, 0, 0); issue(gA, 0, 0, 1);
    issue(gB, 1, 1, 0); issue(gB, 1, 1, 1);
    asm volatile("s_waitcnt vmcnt(4)" ::: "memory");   // tile0 landed
    __builtin_amdgcn_s_barrier();

    f32x4 acc[8][4] = {};
    bf16x8 bq[4][2];

    for (int i = 0; i < NI; ++i) {
        const int kt0 = 2 * i;
#pragma unroll
        for (int p = 0; p < 8; ++p) {
            const int half = p >> 2;
            const int q = p & 3;
            const u16* Ab = L + half * 32768;
            const u16* Bb = L + half * 32768 + 16384;
            if (q == 0) {
#pragma unroll
                for (int ni = 0; ni < 4; ++ni)
#pragma unroll
                    for (int kk = 0; kk < 2; ++kk)
                        bq[ni][kk] = frag64(Bb, wn * 64 + ni * 16, lane, kk);
            }
            bf16x8 af[2][2];
#pragma unroll
            for (int j = 0; j < 2; ++j)
#pragma unroll
                for (int kk = 0; kk < 2; ++kk)
                    af[j][kk] = frag64(Ab, wm * 128 + (2 * q + j) * 16, lane, kk);
            if (p == 0) { if (kt0 + 1 < NT) issue(gA, 0, kt0 + 1, 0); }
            if (p == 1) { if (kt0 + 1 < NT) issue(gA, 0, kt0 + 1, 1);
                          if (kt0 + 2 < NT) issue(gB, 1, kt0 + 2, 0); }
            if (p == 2) { if (kt0 + 2 < NT) issue(gB, 1, kt0 + 2, 1); }
            if (p == 4) { if (kt0 + 2 < NT) issue(gA, 0, kt0 + 2, 0); }
            if (p == 5) { if (kt0 + 2 < NT) issue(gA, 0, kt0 + 2, 1);
                          if (kt0 + 3 < NT) issue(gB, 1, kt0 + 3, 0); }
            if (p == 6) { if (kt0 + 3 < NT) issue(gB, 1, kt0 + 3, 1); }
            if (p == 3) { if (i + 1 < NI) { asm volatile("s_waitcnt vmcnt(4)" ::: "memory"); }
                          else            { asm volatile("s_waitcnt vmcnt(0)" ::: "memory"); } }
            if (p == 7) { if (i + 1 < NI) { asm volatile("s_waitcnt vmcnt(4)" ::: "memory"); } }
            __builtin_amdgcn_s_barrier();
            __builtin_amdgcn_s_setprio(1);
#pragma unroll
            for (int j = 0; j < 2; ++j)
#pragma unroll
                for (int ni = 0; ni < 4; ++ni)
#pragma unroll
                    for (int kk = 0; kk < 2; ++kk)
                        acc[2 * q + j][ni] = __builtin_amdgcn_mfma_f32_16x16x32_bf16(
                            af[j][kk], bq[ni][kk], acc[2 * q + j][ni], 0, 0, 0);
            __builtin_amdgcn_s_setprio(0);
            __builtin_amdgcn_s_barrier();
        }
    }

    const int rsub = (lane >> 4) * 4, csub = lane & 15;
    if constexpr (EPI == 2) {
        u16* ct = L;                                 // [128][264] staged per wm-round
#pragma unroll
        for (int r = 0; r < 2; ++r) {
            if (wm == r) {
#pragma unroll
                for (int mi = 0; mi < 8; ++mi)
#pragma unroll
                    for (int ni = 0; ni < 4; ++ni)
#pragma unroll
                        for (int rr = 0; rr < 4; ++rr)
                            ct[(mi * 16 + rsub + rr) * 264 + wn * 64 + ni * 16 + csub] =
                                f2bf(acc[mi][ni][rr]);
            }
            __syncthreads();
#pragma unroll
            for (int k = 0; k < 8; ++k) {
                const int f = (tid + k * 512) * 8;
                const int r2 = f >> 8, c = f & 255;
                *(u16x8*)&Cout[(size_t)(bm * 256 + r * 128 + r2) * N + bn * 256 + c] =
                    *(const u16x8*)&ct[r2 * 264 + c];
            }
            __syncthreads();
        }
    } else {
        u16* ct = L;                                 // [256][132]
#pragma unroll
        for (int mi = 0; mi < 8; ++mi)
#pragma unroll
            for (int g = 0; g < 2; ++g)
#pragma unroll
                for (int rr = 0; rr < 4; ++rr) {
                    const float u1 = acc[mi][2 * g][rr];
                    const float u3 = acc[mi][2 * g + 1][rr];
                    ct[(wm * 128 + mi * 16 + rsub + rr) * 132 + wn * 32 + g * 16 + csub] =
                        f2bf(u1 * sigm(u1) * u3);
                }
        __syncthreads();
#pragma unroll
        for (int k = 0; k < 8; ++k) {
            const int f = (tid + k * 512) * 8;
            const int r2 = f >> 7, c = f & 127;
            *(u16x8*)&Cout[(size_t)(bm * 256 + r2) * N + bn * 128 + c] =
                *(const u16x8*)&ct[r2 * 132 + c];
        }
    }
}

// ---------------- bf16 GEMM (skinny N=1024): tile 128(M)x64(N), 8 waves (4Mx2N),
// 3-deep ring buffer with counted vmcnt (loads stay in flight across barriers)
__global__ __launch_bounds__(512) void k_gemm_skinny(const u16* __restrict__ A, const u16* __restrict__ Bt,
                                                     float* __restrict__ Cout, const float* __restrict__ Res,
                                                     int N, int Kd) {
    __shared__ __align__(16) char smem[73728];   // 3 bufs x (A 16KB | B 8KB)
    const int q = (int)gridDim.x >> 3;
    const int bid = blockIdx.x;
    const int wg = (bid & 7) * q + (bid >> 3);   // XCD-contiguous
    const int bm = wg & 15, bn = wg >> 4;        // M blocks = 16
    const int tid = threadIdx.x, lane = tid & 63, wave = tid >> 6;
    const int wm = wave >> 1, wn = wave & 1;     // 4 x 2 wave grid, wave tile 32x32

    const int srow = tid >> 3;                   // 0..63
    const int scol = ((tid & 7) ^ ((tid >> 3) & 7)) * 8;
    const u16* gA = A + (size_t)(bm * 128 + srow) * Kd + scol;
    const u16* gB = Bt + (size_t)(bn * 64 + srow) * Kd + scol;

    f32x4 acc[2][2] = {};
    const int NT = Kd >> 6;                      // >= 32 for all uses

    auto issue = [&](int kt, int buf) {          // 3 vmem instructions per wave
        const int k0 = kt << 6;
        u16* Ab = (u16*)(smem + buf * 24576);
        u16* Bb = Ab + 8192;
        async16(gA + k0, Ab + wave * 512);
        async16(gA + (size_t)64 * Kd + k0, Ab + 4096 + wave * 512);
        async16(gB + k0, Bb + wave * 512);
    };

    issue(0, 0); issue(1, 1); issue(2, 2);
    asm volatile("s_waitcnt vmcnt(6)" ::: "memory");   // tile 0 landed
    __syncthreads();

    int cur = 0;
    for (int t = 0; t < NT; ++t) {
        const u16* Ab = (const u16*)(smem + cur * 24576);
        const u16* Bb = Ab + 8192;
#pragma unroll
        for (int kk = 0; kk < 2; ++kk) {
            bf16x8 af[2], bfr[2];
#pragma unroll
            for (int mi = 0; mi < 2; ++mi) af[mi] = frag64(Ab, wm * 32 + mi * 16, lane, kk);
#pragma unroll
            for (int ni = 0; ni < 2; ++ni) bfr[ni] = frag64(Bb, wn * 32 + ni * 16, lane, kk);
#pragma unroll
            for (int mi = 0; mi < 2; ++mi)
#pragma unroll
                for (int ni = 0; ni < 2; ++ni)
                    acc[mi][ni] = __builtin_amdgcn_mfma_f32_16x16x32_bf16(af[mi], bfr[ni], acc[mi][ni], 0, 0, 0);
        }
        __syncthreads();                          // all waves done reading buf[cur]
        if (t + 3 < NT) issue(t + 3, cur);        // refill the just-freed buffer
        if (t + 1 < NT) {                         // make tile t+1 visible
            if (t + 3 < NT)      { asm volatile("s_waitcnt vmcnt(6)" ::: "memory"); }
            else if (t + 2 < NT) { asm volatile("s_waitcnt vmcnt(3)" ::: "memory"); }
            else                 { asm volatile("s_waitcnt vmcnt(0)" ::: "memory"); }
            __syncthreads();
        }
        cur = (cur == 2) ? 0 : cur + 1;
    }
    __syncthreads();

    const int rsub = (lane >> 4) * 4;
    const int csub = lane & 15;
    float* ctile = (float*)smem;                 // [128][68]
#pragma unroll
    for (int mi = 0; mi < 2; ++mi)
#pragma unroll
        for (int ni = 0; ni < 2; ++ni)
#pragma unroll
            for (int r = 0; r < 4; ++r)
                ctile[(wm * 32 + mi * 16 + rsub + r) * 68 + wn * 32 + ni * 16 + csub] = acc[mi][ni][r];
    __syncthreads();
#pragma unroll
    for (int k = 0; k < 4; ++k) {
        const int f = (tid + k * 512) * 4;
        const int r = f >> 6, c = f & 63;
        float4 v = *(const float4*)&ctile[r * 68 + c];
        const float4 rv = *(const float4*)&Res[(size_t)(bm * 128 + r) * N + bn * 64 + c];
        v.x += rv.x; v.y += rv.y; v.z += rv.z; v.w += rv.w;
        *(float4*)&Cout[(size_t)(bm * 128 + r) * N + bn * 64 + c] = v;
    }
}

// ---------------- chunked gated delta rule: stage 1 (per b,h,chunk — fully parallel)
// FUSED conv(4)+silu+l2norm + beta/log-decay; T = (I+A)^{-1} via doubling; exports M, Qc, W,
// U0T and affine-recurrence operands A2m = -(W^T·Kc^T), B = U0T·Kc^T. KcT kept in LDS only.
__global__ __launch_bounds__(256) void k_scan1(
    const u16* __restrict__ P, const float* __restrict__ cwq, const float* __restrict__ cwk,
    const float* __restrict__ cwv, const float* __restrict__ A_log, const float* __restrict__ dtb,
    u16* __restrict__ CHW, u16* __restrict__ CHM, u16* __restrict__ CHQc,
    u16* __restrict__ CHU0T, float* __restrict__ CHcC,
    u16* __restrict__ CHA2m, u16* __restrict__ CHB) {
    __shared__ __align__(16) char sm[75008];
    u16* Ql   = (u16*)(sm);            // 8KB
    u16* Kl   = (u16*)(sm + 8192);     // 8KB   (later: W^T image)
    u16* VTb  = (u16*)(sm + 16384);    // 16KB
    u16* KT1b = (u16*)(sm + 32768);    // 8KB
    u16* Mim  = (u16*)(sm + 40960);    // 8KB   (phase0: Vtmp low;  later: U0T image low)
    u16* MTim = (u16*)(sm + 49152);    // 8KB   (phase0: Vtmp high; later: U0T image high)
    u16* Tb   = (u16*)(sm + 57344);    // 8KB
    u16* KcTl = (u16*)(sm + 65536);    // 8KB   KcT image, LDS-resident
    float* Tl    = (float*)sm;         // 16KB fp32 T master, overlays Ql+Kl after 2a
    float* gcs   = (float*)(sm + 73728);
    float* betal = (float*)(sm + 73984);
    float* egcs  = (float*)(sm + 74240);
    float* egcsC = (float*)(sm + 74496);
    float* bkc   = (float*)(sm + 74752);
    u16* Vtmp = Mim;                   // [64][128] linear conv-v staging (16KB)

    const int blk = blockIdx.x;                      // bb*256 + h*16 + ch
    const int bb = blk >> 8, h = (blk >> 4) & 15, ch = blk & 15;
    const int bhc = blk;
    const int tid = threadIdx.x, lane = tid & 63, wave = tid >> 6;
    const long rowbase = (long)bb * 1024 + ch * 64;
    const int tbase = wave * 16 + ((lane >> 4) << 2);

    // ---- phase 0 (fused conv): beta/log-decay scalars + conv/silu/l2norm into Ql/Kl/Vtmp
    if (tid < 64) {
        const long pr = (rowbase + tid) * (long)N1P;
        betal[tid] = sigm(bf2f(P[pr + 4096 + h]));
        const float a = bf2f(P[pr + 4112 + h]) + dtb[h];
        const float sp = (a > 15.f) ? a : log1pf(__expf(a));
        gcs[tid] = -__expf(A_log[h]) * sp;           // raw log decay (cumsum later)
    }
    {
        const int g = tid & 31, rb2 = tid >> 5;      // col-group of 8, row-block of 8
        int colbase; const float* cw;
        if (g < 8)       { const int cc = h * 64 + g * 8;        colbase = cc;        cw = cwq + cc * 4; }
        else if (g < 16) { const int cc = h * 64 + (g - 8) * 8;   colbase = 1024 + cc; cw = cwk + cc * 4; }
        else             { const int cc = h * 128 + (g - 16) * 8; colbase = 2048 + cc; cw = cwv + cc * 4; }
        float4 wgt[8];
#pragma unroll
        for (int e = 0; e < 8; ++e) wgt[e] = ((const float4*)cw)[e];
        u16x8 taps[11];                               // sliding window rows rb2*8-3 .. rb2*8+7
#pragma unroll
        for (int j = 0; j < 11; ++j) {
            const int tloc = ch * 64 + rb2 * 8 - 3 + j;
            if (tloc >= 0) taps[j] = *(const u16x8*)&P[((long)bb * 1024 + tloc) * N1P + colbase];
            else           taps[j] = u16x8{};
        }
#pragma unroll
        for (int r = 0; r < 8; ++r) {
            float y[8];
            float ss = 0.f;
#pragma unroll
            for (int e = 0; e < 8; ++e) {
                float v = bf2f(taps[r][e]) * wgt[e].x + bf2f(taps[r + 1][e]) * wgt[e].y +
                          bf2f(taps[r + 2][e]) * wgt[e].z + bf2f(taps[r + 3][e]) * wgt[e].w;
                v = v * sigm(v);
                y[e] = v;
                ss += v * v;
            }
            ss += __shfl_xor(ss, 1); ss += __shfl_xor(ss, 2); ss += __shfl_xor(ss, 4);
            const float rn = rsqrtf(ss + 1e-6f);
            const float sc = (g < 8) ? rn * 0.125f : (g < 16 ? rn : 1.f);
            u16x8 o;
#pragma unroll
            for (int e = 0; e < 8; ++e) o[e] = f2bf(y[e] * sc);
            const int row = rb2 * 8 + r;
            if (g < 16) {
                u16* dst = (g < 8) ? Ql : Kl;
                *(u16x8*)((char*)dst + row * 128 + (((g & 7) ^ (row & 7)) << 4)) = o;
            } else {
                *(u16x8*)&Vtmp[row * 128 + (g - 16) * 8] = o;
            }
        }
    }
    __syncthreads();

    // ---- phase 1: cumsum + exp tables (wave 0); VTb build from Vtmp; QK^T / KK^T
    if (wave == 0) {
        float g = gcs[lane];
#pragma unroll
        for (int off = 1; off < 64; off <<= 1) {
            float n = __shfl_up(g, off, 64);
            if (lane >= off) g += n;
        }
        gcs[lane] = g;
        const float gC = __shfl(g, 63);
        const float eg = __expf(g);
        egcs[lane] = eg;
        egcsC[lane] = __expf(gC - g);
        bkc[lane] = betal[lane] * eg;
    }
    for (int u = tid; u < 1024; u += 256) {          // VTb[dv][c] = beta_c * V[c][dv]
        int r = u >> 4, c8 = u & 15;
        u16x8 vv = *(const u16x8*)&Vtmp[r * 128 + c8 * 8];
        float bsc = betal[r];
#pragma unroll
        for (int j = 0; j < 8; ++j) {
            int dv = c8 * 8 + j;
            *(u16*)((char*)VTb + swz64(dv, r)) = f2bf(bf2f(vv[j]) * bsc);
        }
    }
    f32x4 aQK[4] = {}, aKK[4] = {};
#pragma unroll
    for (int nt = 0; nt < 4; ++nt)
#pragma unroll
        for (int kk = 0; kk < 2; ++kk) {
            bf16x8 bq = frag64(Kl, nt * 16, lane, kk);
            aQK[nt] = __builtin_amdgcn_mfma_f32_16x16x32_bf16(frag64(Ql, wave * 16, lane, kk), bq, aQK[nt], 0, 0, 0);
            aKK[nt] = __builtin_amdgcn_mfma_f32_16x16x32_bf16(frag64(Kl, wave * 16, lane, kk), bq, aKK[nt], 0, 0, 0);
        }
    __syncthreads();   // gcs/exp tables + VTb published; Vtmp dead -> Mim/MTim writable

    // ---- phase 2a: CHM, M0 images (MT vectorized), Qc, KT1b, KcT(LDS)
    float am[4][4];
#pragma unroll
    for (int nt = 0; nt < 4; ++nt) {
        const int i = nt * 16 + (lane & 15);
        u16x4 mtv;
#pragma unroll
        for (int reg = 0; reg < 4; ++reg) {
            const int t = tbase + reg;
            const float dec = __expf(gcs[t] - gcs[i]);
            const float mv = (i <= t) ? dec * aQK[nt][reg] : 0.f;
            *(u16*)((char*)CHM + (size_t)bhc * 8192 + swz64(t, i)) = f2bf(mv);
            const float a = (i < t) ? betal[t] * dec * aKK[nt][reg] : 0.f;
            am[nt][reg] = -a;
            const u16 amb = f2bf(-a);
            *(u16*)((char*)Mim + swz64(t, i)) = amb;
            mtv[reg] = amb;
        }
        *(u16x4*)((char*)MTim + i * 128 + ((((tbase >> 3) ^ (i & 7)) << 4) + (tbase & 7) * 2)) = mtv;
    }
    for (int e = tid; e < 4096; e += 256) {
        const int r = e >> 6, c = e & 63;
        const int ib = swz64(r, c);
        const float qv = bf2f(*(const u16*)((const char*)Ql + ib)) * egcs[r];
        *(u16*)((char*)CHQc + (size_t)bhc * 8192 + ib) = f2bf(qv);
        const float kv = bf2f(*(const u16*)((const char*)Kl + ib));
        const int ob = swz64(c, r);
        *(u16*)((char*)KT1b + ob) = f2bf(kv * bkc[r]);
        *(u16*)((char*)KcTl + ob) = f2bf(kv * egcsC[r]);
    }
    if (tid == 0) CHcC[bhc] = egcs[63];
    __syncthreads();   // Ql/Kl dead; Tl overlay becomes safe

    // ---- phase 2b: T0 = I - A (fp32 master + bf16 image, own rows)
#pragma unroll
    for (int nt = 0; nt < 4; ++nt)
#pragma unroll
        for (int reg = 0; reg < 4; ++reg) {
            const int t = tbase + reg;
            const int i = nt * 16 + (lane & 15);
            const float tv = (t == i) ? 1.f : am[nt][reg];
            Tl[t * 64 + i] = tv;
            *(u16*)((char*)Tb + swz64(t, i)) = f2bf(tv);
        }
    __syncthreads();

    // ---- phase 3: doubling. stage j: M <- M^2 (in place), then T <- T + T*M.
    const int hi = wave * 16 + 15;
#pragma unroll
    for (int j = 1; j <= 5; ++j) {
        f32x4 aM[4] = {};
#pragma unroll
        for (int nt = 0; nt < 4; ++nt) {
            if (nt * 16 > hi - (1 << j)) continue;
#pragma unroll
            for (int kk = 0; kk < 2; ++kk) {
                if (kk * 32 > hi) break;
                aM[nt] = __builtin_amdgcn_mfma_f32_16x16x32_bf16(
                    frag64(Mim, wave * 16, lane, kk), frag64(MTim, nt * 16, lane, kk), aM[nt], 0, 0, 0);
            }
        }
        __syncthreads();
#pragma unroll
        for (int nt = 0; nt < 4; ++nt) {
            const int i = nt * 16 + (lane & 15);
            u16x4 mtv;
#pragma unroll
            for (int reg = 0; reg < 4; ++reg) {
                const int t = tbase + reg;
                const float mv = (t - i >= (1 << j)) ? aM[nt][reg] : 0.f;
                const u16 mb = f2bf(mv);
                *(u16*)((char*)Mim + swz64(t, i)) = mb;
                mtv[reg] = mb;
            }
            *(u16x4*)((char*)MTim + i * 128 + ((((tbase >> 3) ^ (i & 7)) << 4) + (tbase & 7) * 2)) = mtv;
        }
        __syncthreads();
        f32x4 aT[4];
#pragma unroll
        for (int nt = 0; nt < 4; ++nt)
#pragma unroll
            for (int reg = 0; reg < 4; ++reg)
                aT[nt][reg] = Tl[(tbase + reg) * 64 + nt * 16 + (lane & 15)];
#pragma unroll
        for (int nt = 0; nt < 4; ++nt) {
            if (nt * 16 > hi - (1 << j)) continue;
#pragma unroll
            for (int kk = 0; kk < 2; ++kk) {
                if (kk * 32 > hi) break;
                aT[nt] = __builtin_amdgcn_mfma_f32_16x16x32_bf16(
                    frag64(Tb, wave * 16, lane, kk), frag64(MTim, nt * 16, lane, kk), aT[nt], 0, 0, 0);
            }
        }
#pragma unroll
        for (int nt = 0; nt < 4; ++nt)
#pragma unroll
            for (int reg = 0; reg < 4; ++reg) {
                const int t = tbase + reg;
                const int i = nt * 16 + (lane & 15);
                Tl[t * 64 + i] = aT[nt][reg];
                *(u16*)((char*)Tb + swz64(t, i)) = f2bf(aT[nt][reg]);
            }
    }
    __syncthreads();   // doubling done; Tb final; Kl/Mim/MTim reusable

    u16* WTl  = Kl;
    u16* U0Tl = Mim;   // 16KB spans Mim+MTim

    // W = T @ (beta*c*K); write CHW + local W^T image
    {
        f32x4 aW[4] = {};
#pragma unroll
        for (int nt = 0; nt < 4; ++nt)
#pragma unroll
            for (int kk = 0; kk < 2; ++kk) {
                if (kk * 32 > hi) break;
                aW[nt] = __builtin_amdgcn_mfma_f32_16x16x32_bf16(
                    frag64(Tb, wave * 16, lane, kk), frag64(KT1b, nt * 16, lane, kk), aW[nt], 0, 0, 0);
            }
#pragma unroll
        for (int nt = 0; nt < 4; ++nt) {
            const int c = nt * 16 + (lane & 15);
            u16x4 wtv;
#pragma unroll
            for (int reg = 0; reg < 4; ++reg) {
                const int r = tbase + reg;
                const u16 wv = f2bf(aW[nt][reg]);
                *(u16*)((char*)CHW + (size_t)bhc * 8192 + swz64(r, c)) = wv;
                wtv[reg] = wv;
            }
            *(u16x4*)((char*)WTl + c * 128 + ((((tbase >> 3) ^ (c & 7)) << 4) + (tbase & 7) * 2)) = wtv;
        }
    }
    // U0T = (beta*V)^T @ T^T; write CHU0T + local image
#pragma unroll
    for (int rt = 0; rt < 2; ++rt) {
        f32x4 aU[4] = {};
        const int rb = (wave * 2 + rt) * 16;
#pragma unroll
        for (int nt = 0; nt < 4; ++nt)
#pragma unroll
            for (int kk = 0; kk < 2; ++kk) {
                if (kk * 32 > nt * 16 + 15) continue;
                aU[nt] = __builtin_amdgcn_mfma_f32_16x16x32_bf16(
                    frag64(VTb, rb, lane, kk), frag64(Tb, nt * 16, lane, kk), aU[nt], 0, 0, 0);
            }
#pragma unroll
        for (int nt = 0; nt < 4; ++nt)
#pragma unroll
            for (int reg = 0; reg < 4; ++reg) {
                const int dv = rb + ((lane >> 4) << 2) + reg;
                const int c = nt * 16 + (lane & 15);
                const u16 uv = f2bf(aU[nt][reg]);
                *(u16*)((char*)CHU0T + (size_t)bhc * 16384 + swz64(dv, c)) = uv;
                *(u16*)((char*)U0Tl + swz64(dv, c)) = uv;
            }
    }
    __syncthreads();   // WTl/U0Tl ready (KcTl was ready since phase 2a)

    // A2m = -(W^T · Kc^T): out [k][dk], store transposed+negated at [dk][k] (vectorized)
    {
        f32x4 aA[4] = {};
#pragma unroll
        for (int nt = 0; nt < 4; ++nt)
#pragma unroll
            for (int kk = 0; kk < 2; ++kk)
                aA[nt] = __builtin_amdgcn_mfma_f32_16x16x32_bf16(
                    frag64(WTl, wave * 16, lane, kk), frag64(KcTl, nt * 16, lane, kk), aA[nt], 0, 0, 0);
#pragma unroll
        for (int nt = 0; nt < 4; ++nt) {
            const int dk = nt * 16 + (lane & 15);
            u16x4 av;
#pragma unroll
            for (int reg = 0; reg < 4; ++reg) av[reg] = f2bf(-aA[nt][reg]);
            *(u16x4*)((char*)CHA2m + (size_t)bhc * 8192 + dk * 128 +
                      ((((tbase >> 3) ^ (dk & 7)) << 4) + (tbase & 7) * 2)) = av;
        }
    }
    // B = U0T · Kc^T: out [dv][dk]
#pragma unroll
    for (int rt = 0; rt < 2; ++rt) {
        f32x4 aB[4] = {};
        const int rb = (wave * 2 + rt) * 16;
#pragma unroll
        for (int nt = 0; nt < 4; ++nt)
#pragma unroll
            for (int kk = 0; kk < 2; ++kk)
                aB[nt] = __builtin_amdgcn_mfma_f32_16x16x32_bf16(
                    frag64(U0Tl, rb, lane, kk), frag64(KcTl, nt * 16, lane, kk), aB[nt], 0, 0, 0);
#pragma unroll
        for (int nt = 0; nt < 4; ++nt)
#pragma unroll
            for (int reg = 0; reg < 4; ++reg) {
                const int dv = rb + ((lane >> 4) << 2) + reg;
                const int dk = nt * 16 + (lane & 15);
                *(u16*)((char*)CHB + (size_t)bhc * 16384 + swz64(dv, dk)) = f2bf(aB[nt][reg]);
            }
    }
}

// ---------------- scan stage 2: minimal sequential recurrence S' = cC*S + S*A2m + B; exports S0
__global__ __launch_bounds__(256) void k_scan2(
    const u16* __restrict__ CHA2m, const u16* __restrict__ CHB,
    const float* __restrict__ CHcC, u16* __restrict__ CHS0) {
    __shared__ __align__(16) u16 stg[2][8192];   // per buf: A2m 8KB | B(dvh) 8KB
    __shared__ __align__(16) u16 STb[4096];
    __shared__ float ST[64 * 66];
    const int blk = blockIdx.x;
    const int bb = blk >> 5, h = (blk >> 1) & 15, dvh = blk & 1;
    const int bh = bb * 16 + h;
    const int tid = threadIdx.x, lane = tid & 63, wave = tid >> 6;

    for (int e = tid; e < 64 * 66; e += 256) ST[e] = 0.f;
    for (int e = tid; e < 4096; e += 256) STb[e] = 0;

    auto stage = [&](int buf, int ch) {
        const size_t base = (size_t)(bh * 16 + ch);
        const u16* sA = CHA2m + base * 4096;
        const u16* sB = CHB + base * 8192 + dvh * 4096;
#pragma unroll
        for (int r = 0; r < 2; ++r) {
            const int g = r * 256 + tid;
            async16(sA + (size_t)g * 8, &stg[buf][g * 8]);
            async16(sB + (size_t)g * 8, &stg[buf][4096 + g * 8]);
        }
    };
    stage(0, 0);
    int cur = 0;
    for (int ch = 0; ch < 16; ++ch) {
        asm volatile("s_waitcnt vmcnt(0)" ::: "memory");
        __syncthreads();
        if (ch < 15) stage(cur ^ 1, ch + 1);
        const u16* sA2 = &stg[cur][0];
        const u16* sB = &stg[cur][4096];
        f32x4 acc[4] = {};
#pragma unroll
        for (int nt = 0; nt < 4; ++nt)
#pragma unroll
            for (int kk = 0; kk < 2; ++kk)
                acc[nt] = __builtin_amdgcn_mfma_f32_16x16x32_bf16(
                    frag64(STb, wave * 16, lane, kk), frag64(sA2, nt * 16, lane, kk), acc[nt], 0, 0, 0);
        const float cC = CHcC[bh * 16 + ch];
        const size_t sbase = ((size_t)(bh * 16 + ch + 1) * 2 + dvh) * 8192;
#pragma unroll
        for (int nt = 0; nt < 4; ++nt)
#pragma unroll
            for (int reg = 0; reg < 4; ++reg) {
                const int rr = wave * 16 + ((lane >> 4) << 2) + reg;
                const int cc = nt * 16 + (lane & 15);
                const float bv = bf2f(*(const u16*)((const char*)sB + swz64(rr, cc)));
                const float ns = cC * ST[rr * 66 + cc] + acc[nt][reg] + bv;
                ST[rr * 66 + cc] = ns;
                const u16 nb = f2bf(ns);
                *(u16*)((char*)STb + swz64(rr, cc)) = nb;
                if (ch < 15) *(u16*)((char*)CHS0 + sbase + swz64(rr, cc)) = nb;
            }
        cur ^= 1;
    }
}

// ---------------- scan stage 3 (fully parallel): u = U0T - S0*W^T; O = M@u + Qc@S0;
// fused per-head RMSNorm * gate -> OG
__global__ __launch_bounds__(256) void k_scan3(
    const u16* __restrict__ CHM, const u16* __restrict__ CHQc, const u16* __restrict__ CHW,
    const u16* __restrict__ CHU0T, const u16* __restrict__ CHS0, const u16* __restrict__ P,
    const float* __restrict__ onw, u16* __restrict__ OG) {
    __shared__ __align__(16) char sm3[73728];
    u16* sM  = (u16*)sm3;                 // 8KB
    u16* sQc = (u16*)(sm3 + 8192);        // 8KB
    u16* sW  = (u16*)(sm3 + 16384);       // 8KB
    u16* sU  = (u16*)(sm3 + 24576);       // 16KB U0T -> u (in place)
    u16* sS0 = (u16*)(sm3 + 40960);       // 16KB
    u16* sPg = (u16*)(sm3 + 57344);       // 16KB gate tile [64][128]
    const int blk = blockIdx.x;           // bb*256 + h*16 + ch
    const int bb = blk >> 8, h = (blk >> 4) & 15, ch = blk & 15;
    const size_t bhc = blk;
    const int tid = threadIdx.x, lane = tid & 63, wave = tid >> 6;
    const bool hasS0 = (ch != 0);

#pragma unroll
    for (int r = 0; r < 2; ++r) {
        const int g = r * 256 + tid;
        async16(CHM + bhc * 4096 + (size_t)g * 8, sM + g * 8);
        async16(CHQc + bhc * 4096 + (size_t)g * 8, sQc + g * 8);
        async16(CHW + bhc * 4096 + (size_t)g * 8, sW + g * 8);
#pragma unroll
        for (int d = 0; d < 2; ++d) {
            async16(CHU0T + (bhc * 2 + d) * 4096 + (size_t)g * 8, sU + d * 4096 + g * 8);
            if (hasS0)
                async16(CHS0 + (bhc * 2 + d) * 4096 + (size_t)g * 8, sS0 + d * 4096 + g * 8);
        }
    }
    const long prow0 = ((long)bb * 1024 + ch * 64) * N1P + 4128 + h * 128;
#pragma unroll
    for (int k = 0; k < 4; ++k) {
        const int i = tid + k * 256;
        const int row = i >> 4, seg = i & 15;
        async16(P + prow0 + (long)row * N1P + seg * 8, sPg + i * 8);
    }
    asm volatile("s_waitcnt vmcnt(0)" ::: "memory");
    __syncthreads();

    if (hasS0) {
        // u = U0T - S0 * W^T (in place, own rows)
#pragma unroll
        for (int d = 0; d < 2; ++d) {
            f32x4 au[4] = {};
#pragma unroll
            for (int nt = 0; nt < 4; ++nt)
#pragma unroll
                for (int kk = 0; kk < 2; ++kk)
                    au[nt] = __builtin_amdgcn_mfma_f32_16x16x32_bf16(
                        frag64(sS0 + d * 4096, wave * 16, lane, kk), frag64(sW, nt * 16, lane, kk),
                        au[nt], 0, 0, 0);
#pragma unroll
            for (int nt = 0; nt < 4; ++nt)
#pragma unroll
                for (int reg = 0; reg < 4; ++reg) {
                    const int dv = wave * 16 + ((lane >> 4) << 2) + reg;
                    const int c = nt * 16 + (lane & 15);
                    u16* p = (u16*)((char*)sU + d * 8192 + swz64(dv, c));
                    *p = f2bf(bf2f(*p) - au[nt][reg]);
                }
        }
        __syncthreads();
    }

    f32x4 accO[2][4] = {};
#pragma unroll
    for (int d = 0; d < 2; ++d)
#pragma unroll
        for (int nt = 0; nt < 4; ++nt)
#pragma unroll
            for (int kk = 0; kk < 2; ++kk) {
                accO[d][nt] = __builtin_amdgcn_mfma_f32_16x16x32_bf16(
                    frag64(sM, wave * 16, lane, kk), frag64(sU + d * 4096, nt * 16, lane, kk),
                    accO[d][nt], 0, 0, 0);
                if (hasS0)
                    accO[d][nt] = __builtin_amdgcn_mfma_f32_16x16x32_bf16(
                        frag64(sQc, wave * 16, lane, kk), frag64(sS0 + d * 4096, nt * 16, lane, kk),
                        accO[d][nt], 0, 0, 0);
            }

    const int rsub = (lane >> 4) * 4, csub = lane & 15;
    float rn[4];
#pragma unroll
    for (int reg = 0; reg < 4; ++reg) {
        float ss = 0.f;
#pragma unroll
        for (int d = 0; d < 2; ++d)
#pragma unroll
            for (int nt = 0; nt < 4; ++nt) {
                const float v = accO[d][nt][reg];
                ss += v * v;
            }
        ss += __shfl_xor(ss, 1); ss += __shfl_xor(ss, 2);
        ss += __shfl_xor(ss, 4); ss += __shfl_xor(ss, 8);
        rn[reg] = rsqrtf(ss * (1.f / 128.f) + 1e-6f);
    }
    __syncthreads();   // done reading sM/sQc/sW/sU/sS0 -> reuse as out tile
    u16* ct = (u16*)sm3;   // [64][136]
#pragma unroll
    for (int d = 0; d < 2; ++d)
#pragma unroll
        for (int nt = 0; nt < 4; ++nt)
#pragma unroll
            for (int reg = 0; reg < 4; ++reg) {
                const int rr = wave * 16 + rsub + reg;
                const int dv = d * 64 + nt * 16 + csub;
                const float g = bf2f(sPg[rr * 128 + dv]);
                const float val = accO[d][nt][reg] * rn[reg] * onw[dv] * g * sigm(g);
                ct[rr * 136 + dv] = f2bf(val);
            }
    __syncthreads();
#pragma unroll
    for (int k = 0; k < 4; ++k) {
        const int f = (tid + k * 256) * 8;
        const int r2 = f >> 7, c = f & 127;
        *(u16x8*)&OG[(size_t)(bb * 1024 + ch * 64 + r2) * 2048 + h * 128 + c] =
            *(const u16x8*)&ct[r2 * 136 + c];
    }
}

extern "C" void kernel_launch(void* const* d_in, const int* in_sizes, int n_in,
                              void* d_out, int out_size, void* d_ws, size_t ws_size,
                              hipStream_t stream) {
    const float* x   = (const float*)d_in[0];
    const float* n1w = (const float*)d_in[1];
    const float* wq  = (const float*)d_in[2];
    const float* wk  = (const float*)d_in[3];
    const float* wv  = (const float*)d_in[4];
    const float* cq  = (const float*)d_in[5];
    const float* ck  = (const float*)d_in[6];
    const float* cv  = (const float*)d_in[7];
    const float* wb  = (const float*)d_in[8];
    const float* wa  = (const float*)d_in[9];
    const float* Alg = (const float*)d_in[10];
    const float* dtb = (const float*)d_in[11];
    const float* wg  = (const float*)d_in[12];
    const float* onw = (const float*)d_in[13];
    const float* wo  = (const float*)d_in[14];
    const float* n2w = (const float*)d_in[15];
    const float* w1  = (const float*)d_in[16];
    const float* w2  = (const float*)d_in[17];
    const float* w3  = (const float*)d_in[18];

    if (ws_size < 132384768ULL) return;

    char* ws = (char*)d_ws;
    u16*   WcatT = (u16*)(ws + 0);            // [6400][1024] bf16 (CHW/CHM/CHQc reuse)
    u16*   WoT   = (u16*)(ws + 13107200);     // [1024][2048]
    u16*   W13T  = (u16*)(ws + 17301504);     // [5632][1024] group-16 interleaved w1/w3
    u16*   W2T   = (u16*)(ws + 28835840);     // [1024][2816]
    u16*   hA    = (u16*)(ws + 34603008);     // [2048][1024] (h2A reuse)
    u16*   P     = (u16*)(ws + 38797312);     // [2048][6400]
    u16*   Mm    = (u16*)(ws + 65011712);     // [2048][2816] bf16 MLP intermediate
    u16*   OG    = (u16*)(ws + 73400320);     // [2048][2048] bf16
    float* X2    = (float*)(ws + 82051072);   // [2048][1024] fp32
    u16*   CHU0T = (u16*)(ws + 103022592);    // [512][128][64] bf16 image
    float* CHcC  = (float*)(ws + 111411200);  // [512]
    u16*   CHA2m = (u16*)(ws + 111413248);    // [512][64][64] bf16 image (-W^T Kc^T, transposed)
    u16*   CHB   = (u16*)(ws + 115607552);    // [512][128][64] bf16 image (U0T Kc^T)
    u16*   CHS0  = (u16*)(ws + 123996160);    // [512*2][64][64] bf16 image per dvh
    u16*   CHW   = WcatT;                     // [512][64][64] image
    u16*   CHM   = (u16*)(ws + 4194304);
    u16*   CHQc  = (u16*)(ws + 8388608);
    u16*   h2A = hA;

    // fused weight transposes (fp32 [K][N] -> bf16 [N][K]) + rmsnorm-1; tiles 64k x 32n
    TJobs tj;
    tj.j[0] = { wq, WcatT, 1024, 1024,    0, 1, 1024,     0, 32, 0 };   // 512
    tj.j[1] = { wk, WcatT, 1024, 1024, 1024, 1, 1024,   512, 32, 0 };   // 512
    tj.j[2] = { wv, WcatT, 1024, 2048, 2048, 1, 2048,  1024, 64, 0 };   // 1024
    tj.j[3] = { wb, WcatT, 1024,   16, 4096, 1,   16,  2048,  1, 0 };   // 16
    tj.j[4] = { wa, WcatT, 1024,   16, 4112, 1,   16,  2064,  1, 0 };   // 16
    tj.j[5] = { wg, WcatT, 1024, 2048, 4128, 1, 2272,  2080, 71, 0 };   // 1136 (pads rows to 6400)
    tj.j[6] = { wo, WoT,   2048, 1024,    0, 1, 1024,  3216, 32, 0 };   // 1024
    tj.j[7] = { w1, W13T,  1024, 2816,    0, 1, 2816,  4240, 88, 1 };   // 1408 group-16 even
    tj.j[8] = { w3, W13T,  1024, 2816,   16, 1, 2816,  5648, 88, 1 };   // 1408 group-16 odd
    tj.j[9] = { w2, W2T,   2816, 1024,    0, 1, 1024,  7056, 32, 0 };   // 1408 -> blkBase end 8464
    k_transpose_all<<<8464 + 2048, 256, 0, stream>>>(tj, 10, 8464, x, n1w, hA);

    k_gemm256<2><<<200, 512, 0, stream>>>(hA, WcatT, P, N1P, 1024);

    k_scan1<<<512, 256, 0, stream>>>(P, cq, ck, cv, Alg, dtb, CHW, CHM, CHQc, CHU0T,
                                     CHcC, CHA2m, CHB);
    k_scan2<<<64, 256, 0, stream>>>(CHA2m, CHB, CHcC, CHS0);
    k_scan3<<<512, 256, 0, stream>>>(CHM, CHQc, CHW, CHU0T, CHS0, P, onw, OG);

    k_gemm_skinny<<<256, 512, 0, stream>>>(OG, WoT, X2, x, 1024, 2048);

    k_rmsnorm<<<2048, 256, 0, stream>>>(X2, n2w, h2A);
    k_gemm256<3><<<176, 512, 0, stream>>>(h2A, W13T, Mm, 2816, 1024);  // fused silu(u1)*u3
    k_gemm_skinny<<<256, 512, 0, stream>>>(Mm, W2T, (float*)d_out, X2, 1024, 2816);
}

// Round 18
// 216.528 us; speedup vs baseline: 1.0613x; 1.0613x over previous
//
#include <hip/hip_runtime.h>
#include <stdint.h>

typedef unsigned short u16;
typedef float f32x4 __attribute__((ext_vector_type(4)));
typedef __bf16 bf16x8 __attribute__((ext_vector_type(8)));
typedef unsigned short u16x8 __attribute__((ext_vector_type(8)));
typedef unsigned short u16x4 __attribute__((ext_vector_type(4)));

#define N1P 6400   // padded concat width: q(1024)|k(1024)|v(2048)|b(16)|a(16)|g(2048)|pad(224)

__device__ __forceinline__ u16 f2bf(float f) {
    union { float f; uint32_t u; } v; v.f = f;
    uint32_t u = v.u;
    return (u16)((u + 0x7FFFu + ((u >> 16) & 1u)) >> 16);
}
__device__ __forceinline__ float bf2f(u16 h) {
    union { uint32_t u; float f; } v; v.u = ((uint32_t)h) << 16; return v.f;
}
__device__ __forceinline__ float sigm(float x) { return 1.f / (1.f + __expf(-x)); }

__device__ __forceinline__ void async16(const u16* g, u16* l) {
    __builtin_amdgcn_global_load_lds((const __attribute__((address_space(1))) void*)g,
                                     (__attribute__((address_space(3))) void*)l, 16, 0, 0);
}

// byte offset inside a [R][64] bf16 "swizzled image": 16B units XOR'd with row&7
__device__ __forceinline__ int swz64(int row, int col) {
    return row * 128 + ((((col >> 3) ^ (row & 7)) << 3) + (col & 7)) * 2;
}
// MFMA fragment read from a swizzled [R][64] bf16 image (rows rowbase..rowbase+15, K-offset kk*32)
__device__ __forceinline__ bf16x8 frag64(const u16* m, int rowbase, int lane, int kk) {
    const int row = rowbase + (lane & 15);
    const int unit = (lane >> 4) + (kk << 2);
    return *(const bf16x8*)((const char*)m + row * 128 + ((unit ^ (row & 7)) << 4));
}

// ---------------- fused transpose + fp32->bf16 convert (10 weights) + rmsnorm-1 (one launch)
// Transpose tile: 64(k) x 32(n); writes one u16x8 per thread.
// mode 0: dst row = rowOff + n*rowStride ; mode 1: dst row = rowOff + (n>>4)*32 + (n&15)
struct TJob { const float* src; u16* dst; int rows, cols, rowOff, rowStride, nOut, blkBase, gx, mode; };
struct TJobs { TJob j[10]; };

__global__ __launch_bounds__(256) void k_transpose_all(TJobs jobs, int njobs, int rmsBase,
                                                       const float* __restrict__ xin,
                                                       const float* __restrict__ n1w,
                                                       u16* __restrict__ hOut) {
    __shared__ float tile[64][33];
    const int bid = blockIdx.x;
    const int tid = threadIdx.x;
    if (bid >= rmsBase) {
        // ---- rmsnorm row (D=1024, fp32 -> bf16)
        const int row = bid - rmsBase;
        const int lane = tid & 63, wave = tid >> 6;
        const float4 v = ((const float4*)(xin + (size_t)row * 1024))[tid];
        float ss = v.x * v.x + v.y * v.y + v.z * v.z + v.w * v.w;
#pragma unroll
        for (int o = 1; o < 64; o <<= 1) ss += __shfl_xor(ss, o);
        float* sred = &tile[0][0];
        if (lane == 0) sred[wave] = ss;
        __syncthreads();
        const float tot = sred[0] + sred[1] + sred[2] + sred[3];
        const float rn = rsqrtf(tot * (1.f / 1024.f) + 1e-6f);
        const float4 wv = ((const float4*)n1w)[tid];
        uint2 pk;
        pk.x = (uint32_t)f2bf(v.x * rn * wv.x) | ((uint32_t)f2bf(v.y * rn * wv.y) << 16);
        pk.y = (uint32_t)f2bf(v.z * rn * wv.z) | ((uint32_t)f2bf(v.w * rn * wv.w) << 16);
        *(uint2*)&hOut[(size_t)row * 1024 + tid * 4] = pk;
        return;
    }
    int ji = 0;
#pragma unroll
    for (int i = 1; i < 10; ++i)
        if (i < njobs && bid >= jobs.j[i].blkBase) ji = i;
    const TJob J = jobs.j[ji];
    const int bx = bid - J.blkBase;
    const int n0 = (bx % J.gx) * 32, k0 = (bx / J.gx) * 64;
    const int tx = tid & 31, ty = tid >> 5;      // 32 x 8
    const int c = n0 + tx;
    const bool cok = (c < J.cols);
#pragma unroll
    for (int i = 0; i < 8; ++i) {
        const int r = k0 + i * 8 + ty;           // rows are multiples of 64 -> always in range
        tile[i * 8 + ty][tx] = cok ? J.src[(size_t)r * J.cols + c] : 0.f;
    }
    __syncthreads();
    const int n = tid >> 3, seg = tid & 7;
    const int ng = n0 + n;
    if (ng < J.nOut) {
        u16x8 o;
#pragma unroll
        for (int e = 0; e < 8; ++e) o[e] = f2bf(tile[seg * 8 + e][n]);
        const int drow = (J.mode == 0) ? (J.rowOff + ng * J.rowStride)
                                       : (J.rowOff + ((ng >> 4) << 5) + (ng & 15));
        *(u16x8*)&J.dst[(size_t)drow * J.rows + k0 + seg * 8] = o;
    }
}

// ---------------- rmsnorm over D=1024, fp32 in -> bf16 out (used for norm-2 only)
__global__ __launch_bounds__(256) void k_rmsnorm(const float* __restrict__ x, const float* __restrict__ w,
                                                 u16* __restrict__ out) {
    const int row = blockIdx.x, tid = threadIdx.x, lane = tid & 63, wave = tid >> 6;
    const float4 v = ((const float4*)(x + (size_t)row * 1024))[tid];
    float ss = v.x * v.x + v.y * v.y + v.z * v.z + v.w * v.w;
#pragma unroll
    for (int o = 1; o < 64; o <<= 1) ss += __shfl_xor(ss, o);
    __shared__ float sred[4];
    if (lane == 0) sred[wave] = ss;
    __syncthreads();
    const float tot = sred[0] + sred[1] + sred[2] + sred[3];
    const float rn = rsqrtf(tot * (1.f / 1024.f) + 1e-6f);
    const float4 wv = ((const float4*)w)[tid];
    uint2 pk;
    pk.x = (uint32_t)f2bf(v.x * rn * wv.x) | ((uint32_t)f2bf(v.y * rn * wv.y) << 16);
    pk.y = (uint32_t)f2bf(v.z * rn * wv.z) | ((uint32_t)f2bf(v.w * rn * wv.w) << 16);
    *(uint2*)&out[(size_t)row * 1024 + tid * 4] = pk;
}

// ---------------- 256x256 8-phase GEMM (T2+T3+T4+T5), BK=64, 8 waves (2Mx4N), wave tile 128x64.
// A[2048][Kd] bf16 row-major, Bt[N'][Kd] bf16 row-major. Kd must be multiple of 128.
// EPI 2 = bf16 store (width N); EPI 3 = fused silu(u1)*u3, B group-16-interleaved (out width N)
template <int EPI>
__global__ __launch_bounds__(512, 2) void k_gemm256(const u16* __restrict__ A, const u16* __restrict__ Bt,
                                                    u16* __restrict__ Cout, int N, int Kd) {
    __shared__ __align__(16) u16 L[65536];   // 128KB: buf{0,1} x (A 256x64 | B 256x64) swizzled images
    const int q8 = (int)gridDim.x >> 3;
    const int bid = blockIdx.x;
    const int wg = (bid & 7) * q8 + (bid >> 3);      // XCD-contiguous
    const int bm = wg & 7, bn = wg >> 3;             // M blocks = 2048/256 = 8
    const int tid = threadIdx.x, lane = tid & 63, wave = tid >> 6;
    const int wm = wave >> 2, wn = wave & 3;         // 2 x 4 wave grid

    const int scol = ((tid & 7) ^ ((tid >> 3) & 7)) * 8;  // pre-swizzled source granule
    const u16* gA = A + (size_t)(bm * 256 + (tid >> 3)) * Kd + scol;
    const u16* gB = Bt + (size_t)(bn * 256 + (tid >> 3)) * Kd + scol;
    u16* dstT = L + tid * 8;

    const int NT = Kd >> 6;
    const int NI = NT >> 1;

    auto issue = [&](const u16* g, int mtx, int kt, int h) {   // one half-tile = 2 gloads/thread
        u16* d = dstT + (kt & 1) * 32768 + mtx * 16384 + h * 8192;
        const u16* s = g + (size_t)(h * 128) * Kd + kt * 64;
        async16(s, d);
        async16(s + (size_t)64 * Kd, d + 4096);
    };

    issue(gB, 1, 0, 0); issue(gB, 1, 0, 1);
    issue(gA, 0, 0, 0); issue(gA, 0, 0, 1);
    issue(gB, 1, 1, 0); issue(gB, 1, 1, 1);
    asm volatile("s_waitcnt vmcnt(4)" ::: "memory");   // tile0 landed
    __builtin_amdgcn_s_barrier();

    f32x4 acc[8][4] = {};
    bf16x8 bq[4][2];

    for (int i = 0; i < NI; ++i) {
        const int kt0 = 2 * i;
#pragma unroll
        for (int p = 0; p < 8; ++p) {
            const int half = p >> 2;
            const int q = p & 3;
            const u16* Ab = L + half * 32768;
            const u16* Bb = L + half * 32768 + 16384;
            if (q == 0) {
#pragma unroll
                for (int ni = 0; ni < 4; ++ni)
#pragma unroll
                    for (int kk = 0; kk < 2; ++kk)
                        bq[ni][kk] = frag64(Bb, wn * 64 + ni * 16, lane, kk);
            }
            bf16x8 af[2][2];
#pragma unroll
            for (int j = 0; j < 2; ++j)
#pragma unroll
                for (int kk = 0; kk < 2; ++kk)
                    af[j][kk] = frag64(Ab, wm * 128 + (2 * q + j) * 16, lane, kk);
            if (p == 0) { if (kt0 + 1 < NT) issue(gA, 0, kt0 + 1, 0); }
            if (p == 1) { if (kt0 + 1 < NT) issue(gA, 0, kt0 + 1, 1);
                          if (kt0 + 2 < NT) issue(gB, 1, kt0 + 2, 0); }
            if (p == 2) { if (kt0 + 2 < NT) issue(gB, 1, kt0 + 2, 1); }
            if (p == 4) { if (kt0 + 2 < NT) issue(gA, 0, kt0 + 2, 0); }
            if (p == 5) { if (kt0 + 2 < NT) issue(gA, 0, kt0 + 2, 1);
                          if (kt0 + 3 < NT) issue(gB, 1, kt0 + 3, 0); }
            if (p == 6) { if (kt0 + 3 < NT) issue(gB, 1, kt0 + 3, 1); }
            if (p == 3) { if (i + 1 < NI) { asm volatile("s_waitcnt vmcnt(4)" ::: "memory"); }
                          else            { asm volatile("s_waitcnt vmcnt(0)" ::: "memory"); } }
            if (p == 7) { if (i + 1 < NI) { asm volatile("s_waitcnt vmcnt(4)" ::: "memory"); } }
            __builtin_amdgcn_s_barrier();
            __builtin_amdgcn_s_setprio(1);
#pragma unroll
            for (int j = 0; j < 2; ++j)
#pragma unroll
                for (int ni = 0; ni < 4; ++ni)
#pragma unroll
                    for (int kk = 0; kk < 2; ++kk)
                        acc[2 * q + j][ni] = __builtin_amdgcn_mfma_f32_16x16x32_bf16(
                            af[j][kk], bq[ni][kk], acc[2 * q + j][ni], 0, 0, 0);
            __builtin_amdgcn_s_setprio(0);
            __builtin_amdgcn_s_barrier();
        }
    }

    const int rsub = (lane >> 4) * 4, csub = lane & 15;
    if constexpr (EPI == 2) {
        u16* ct = L;                                 // [128][264] staged per wm-round
#pragma unroll
        for (int r = 0; r < 2; ++r) {
            if (wm == r) {
#pragma unroll
                for (int mi = 0; mi < 8; ++mi)
#pragma unroll
                    for (int ni = 0; ni < 4; ++ni)
#pragma unroll
                        for (int rr = 0; rr < 4; ++rr)
                            ct[(mi * 16 + rsub + rr) * 264 + wn * 64 + ni * 16 + csub] =
                                f2bf(acc[mi][ni][rr]);
            }
            __syncthreads();
#pragma unroll
            for (int k = 0; k < 8; ++k) {
                const int f = (tid + k * 512) * 8;
                const int r2 = f >> 8, c = f & 255;
                *(u16x8*)&Cout[(size_t)(bm * 256 + r * 128 + r2) * N + bn * 256 + c] =
                    *(const u16x8*)&ct[r2 * 264 + c];
            }
            __syncthreads();
        }
    } else {
        u16* ct = L;                                 // [256][132]
#pragma unroll
        for (int mi = 0; mi < 8; ++mi)
#pragma unroll
            for (int g = 0; g < 2; ++g)
#pragma unroll
                for (int rr = 0; rr < 4; ++rr) {
                    const float u1 = acc[mi][2 * g][rr];
                    const float u3 = acc[mi][2 * g + 1][rr];
                    ct[(wm * 128 + mi * 16 + rsub + rr) * 132 + wn * 32 + g * 16 + csub] =
                        f2bf(u1 * sigm(u1) * u3);
                }
        __syncthreads();
#pragma unroll
        for (int k = 0; k < 8; ++k) {
            const int f = (tid + k * 512) * 8;
            const int r2 = f >> 7, c = f & 127;
            *(u16x8*)&Cout[(size_t)(bm * 256 + r2) * N + bn * 128 + c] =
                *(const u16x8*)&ct[r2 * 132 + c];
        }
    }
}

// ---------------- 2-phase bf16 GEMM (skinny N=1024): tile 128(M)x64(N), 8 waves (4Mx2N), dbuf
// bn-fastest XCD ordering: each XCD chunk = 16 bn x 2 bm -> reuses full B in L2, 2 A-panels.
__global__ __launch_bounds__(512) void k_gemm_skinny(const u16* __restrict__ A, const u16* __restrict__ Bt,
                                                     float* __restrict__ Cout, const float* __restrict__ Res,
                                                     int N, int Kd) {
    __shared__ __align__(16) char smem[49152];
    u16* Asb = (u16*)smem;                       // [2][128*64]
    u16* Bsb = (u16*)(smem + 32768);             // [2][64*64]
    const int q = (int)gridDim.x >> 3;
    const int bid = blockIdx.x;
    const int wg = (bid & 7) * q + (bid >> 3);   // XCD-contiguous
    const int bn = wg & 15, bm = wg >> 4;        // bn fastest -> B-matrix locality per XCD
    const int tid = threadIdx.x, lane = tid & 63, wave = tid >> 6;
    const int wm = wave >> 1, wn = wave & 1;     // 4 x 2 wave grid, wave tile 32x32

    const int srow = tid >> 3;                   // 0..63
    const int scol = ((tid & 7) ^ ((tid >> 3) & 7)) * 8;
    const u16* gA = A + (size_t)(bm * 128 + srow) * Kd + scol;
    const u16* gB = Bt + (size_t)(bn * 64 + srow) * Kd + scol;

    f32x4 acc[2][2] = {};
    const int NT = Kd >> 6;

    async16(gA, Asb + wave * 512);
    async16(gA + (size_t)64 * Kd, Asb + 4096 + wave * 512);
    async16(gB, Bsb + wave * 512);
    asm volatile("s_waitcnt vmcnt(0)" ::: "memory");
    __syncthreads();

    int buf = 0;
    for (int t = 0; t < NT; ++t) {
        if (t + 1 < NT) {
            const int k0 = (t + 1) << 6;
            const int ba = (buf ^ 1) * 8192, bb2 = (buf ^ 1) * 4096;
            async16(gA + k0, Asb + ba + wave * 512);
            async16(gA + (size_t)64 * Kd + k0, Asb + ba + 4096 + wave * 512);
            async16(gB + k0, Bsb + bb2 + wave * 512);
        }
        const u16* Ab = Asb + buf * 8192;
        const u16* Bb = Bsb + buf * 4096;
#pragma unroll
        for (int kk = 0; kk < 2; ++kk) {
            bf16x8 af[2], bfr[2];
#pragma unroll
            for (int mi = 0; mi < 2; ++mi) af[mi] = frag64(Ab, wm * 32 + mi * 16, lane, kk);
#pragma unroll
            for (int ni = 0; ni < 2; ++ni) bfr[ni] = frag64(Bb, wn * 32 + ni * 16, lane, kk);
#pragma unroll
            for (int mi = 0; mi < 2; ++mi)
#pragma unroll
                for (int ni = 0; ni < 2; ++ni)
                    acc[mi][ni] = __builtin_amdgcn_mfma_f32_16x16x32_bf16(af[mi], bfr[ni], acc[mi][ni], 0, 0, 0);
        }
        asm volatile("s_waitcnt vmcnt(0)" ::: "memory");
        __syncthreads();
        buf ^= 1;
    }

    const int rsub = (lane >> 4) * 4;
    const int csub = lane & 15;
    float* ctile = (float*)smem;                 // [128][68]
#pragma unroll
    for (int mi = 0; mi < 2; ++mi)
#pragma unroll
        for (int ni = 0; ni < 2; ++ni)
#pragma unroll
            for (int r = 0; r < 4; ++r)
                ctile[(wm * 32 + mi * 16 + rsub + r) * 68 + wn * 32 + ni * 16 + csub] = acc[mi][ni][r];
    __syncthreads();
#pragma unroll
    for (int k = 0; k < 4; ++k) {
        const int f = (tid + k * 512) * 4;
        const int r = f >> 6, c = f & 63;
        float4 v = *(const float4*)&ctile[r * 68 + c];
        const float4 rv = *(const float4*)&Res[(size_t)(bm * 128 + r) * N + bn * 64 + c];
        v.x += rv.x; v.y += rv.y; v.z += rv.z; v.w += rv.w;
        *(float4*)&Cout[(size_t)(bm * 128 + r) * N + bn * 64 + c] = v;
    }
}

// ---------------- chunked gated delta rule: stage 1 (per b,h,chunk — fully parallel)
// FUSED conv(4)+silu+l2norm + beta/log-decay; T = (I+A)^{-1} via doubling; exports M, Qc, W,
// U0T and affine-recurrence operands A2m = -(W^T·Kc^T), B = U0T·Kc^T. KcT kept in LDS only.
__global__ __launch_bounds__(256) void k_scan1(
    const u16* __restrict__ P, const float* __restrict__ cwq, const float* __restrict__ cwk,
    const float* __restrict__ cwv, const float* __restrict__ A_log, const float* __restrict__ dtb,
    u16* __restrict__ CHW, u16* __restrict__ CHM, u16* __restrict__ CHQc,
    u16* __restrict__ CHU0T, float* __restrict__ CHcC,
    u16* __restrict__ CHA2m, u16* __restrict__ CHB) {
    __shared__ __align__(16) char sm[75008];
    u16* Ql   = (u16*)(sm);            // 8KB
    u16* Kl   = (u16*)(sm + 8192);     // 8KB   (later: W^T image)
    u16* VTb  = (u16*)(sm + 16384);    // 16KB
    u16* KT1b = (u16*)(sm + 32768);    // 8KB
    u16* Mim  = (u16*)(sm + 40960);    // 8KB   (phase0: Vtmp low;  later: U0T image low)
    u16* MTim = (u16*)(sm + 49152);    // 8KB   (phase0: Vtmp high; later: U0T image high)
    u16* Tb   = (u16*)(sm + 57344);    // 8KB
    u16* KcTl = (u16*)(sm + 65536);    // 8KB   KcT image, LDS-resident
    float* Tl    = (float*)sm;         // 16KB fp32 T master, overlays Ql+Kl after 2a
    float* gcs   = (float*)(sm + 73728);
    float* betal = (float*)(sm + 73984);
    float* egcs  = (float*)(sm + 74240);
    float* egcsC = (float*)(sm + 74496);
    float* bkc   = (float*)(sm + 74752);
    u16* Vtmp = Mim;                   // [64][128] linear conv-v staging (16KB)

    const int blk = blockIdx.x;                      // bb*256 + h*16 + ch
    const int bb = blk >> 8, h = (blk >> 4) & 15, ch = blk & 15;
    const int bhc = blk;
    const int tid = threadIdx.x, lane = tid & 63, wave = tid >> 6;
    const long rowbase = (long)bb * 1024 + ch * 64;
    const int tbase = wave * 16 + ((lane >> 4) << 2);

    // ---- phase 0 (fused conv): beta/log-decay scalars + conv/silu/l2norm into Ql/Kl/Vtmp
    if (tid < 64) {
        const long pr = (rowbase + tid) * (long)N1P;
        betal[tid] = sigm(bf2f(P[pr + 4096 + h]));
        const float a = bf2f(P[pr + 4112 + h]) + dtb[h];
        const float sp = (a > 15.f) ? a : log1pf(__expf(a));
        gcs[tid] = -__expf(A_log[h]) * sp;           // raw log decay (cumsum later)
    }
    {
        const int g = tid & 31, rb2 = tid >> 5;      // col-group of 8, row-block of 8
        int colbase; const float* cw;
        if (g < 8)       { const int cc = h * 64 + g * 8;        colbase = cc;        cw = cwq + cc * 4; }
        else if (g < 16) { const int cc = h * 64 + (g - 8) * 8;   colbase = 1024 + cc; cw = cwk + cc * 4; }
        else             { const int cc = h * 128 + (g - 16) * 8; colbase = 2048 + cc; cw = cwv + cc * 4; }
        float4 wgt[8];
#pragma unroll
        for (int e = 0; e < 8; ++e) wgt[e] = ((const float4*)cw)[e];
        u16x8 taps[11];                               // sliding window rows rb2*8-3 .. rb2*8+7
#pragma unroll
        for (int j = 0; j < 11; ++j) {
            const int tloc = ch * 64 + rb2 * 8 - 3 + j;
            if (tloc >= 0) taps[j] = *(const u16x8*)&P[((long)bb * 1024 + tloc) * N1P + colbase];
            else           taps[j] = u16x8{};
        }
#pragma unroll
        for (int r = 0; r < 8; ++r) {
            float y[8];
            float ss = 0.f;
#pragma unroll
            for (int e = 0; e < 8; ++e) {
                float v = bf2f(taps[r][e]) * wgt[e].x + bf2f(taps[r + 1][e]) * wgt[e].y +
                          bf2f(taps[r + 2][e]) * wgt[e].z + bf2f(taps[r + 3][e]) * wgt[e].w;
                v = v * sigm(v);
                y[e] = v;
                ss += v * v;
            }
            ss += __shfl_xor(ss, 1); ss += __shfl_xor(ss, 2); ss += __shfl_xor(ss, 4);
            const float rn = rsqrtf(ss + 1e-6f);
            const float sc = (g < 8) ? rn * 0.125f : (g < 16 ? rn : 1.f);
            u16x8 o;
#pragma unroll
            for (int e = 0; e < 8; ++e) o[e] = f2bf(y[e] * sc);
            const int row = rb2 * 8 + r;
            if (g < 16) {
                u16* dst = (g < 8) ? Ql : Kl;
                *(u16x8*)((char*)dst + row * 128 + (((g & 7) ^ (row & 7)) << 4)) = o;
            } else {
                *(u16x8*)&Vtmp[row * 128 + (g - 16) * 8] = o;
            }
        }
    }
    __syncthreads();

    // ---- phase 1: cumsum + exp tables (wave 0); VTb build from Vtmp; QK^T / KK^T
    if (wave == 0) {
        float g = gcs[lane];
#pragma unroll
        for (int off = 1; off < 64; off <<= 1) {
            float n = __shfl_up(g, off, 64);
            if (lane >= off) g += n;
        }
        gcs[lane] = g;
        const float gC = __shfl(g, 63);
        const float eg = __expf(g);
        egcs[lane] = eg;
        egcsC[lane] = __expf(gC - g);
        bkc[lane] = betal[lane] * eg;
    }
    for (int u = tid; u < 1024; u += 256) {          // VTb[dv][c] = beta_c * V[c][dv]
        int r = u >> 4, c8 = u & 15;
        u16x8 vv = *(const u16x8*)&Vtmp[r * 128 + c8 * 8];
        float bsc = betal[r];
#pragma unroll
        for (int j = 0; j < 8; ++j) {
            int dv = c8 * 8 + j;
            *(u16*)((char*)VTb + swz64(dv, r)) = f2bf(bf2f(vv[j]) * bsc);
        }
    }
    f32x4 aQK[4] = {}, aKK[4] = {};
#pragma unroll
    for (int nt = 0; nt < 4; ++nt)
#pragma unroll
        for (int kk = 0; kk < 2; ++kk) {
            bf16x8 bq = frag64(Kl, nt * 16, lane, kk);
            aQK[nt] = __builtin_amdgcn_mfma_f32_16x16x32_bf16(frag64(Ql, wave * 16, lane, kk), bq, aQK[nt], 0, 0, 0);
            aKK[nt] = __builtin_amdgcn_mfma_f32_16x16x32_bf16(frag64(Kl, wave * 16, lane, kk), bq, aKK[nt], 0, 0, 0);
        }
    __syncthreads();   // gcs/exp tables + VTb published; Vtmp dead -> Mim/MTim writable

    // ---- phase 2a: CHM, M0 images (MT vectorized), Qc, KT1b, KcT(LDS)
    float am[4][4];
#pragma unroll
    for (int nt = 0; nt < 4; ++nt) {
        const int i = nt * 16 + (lane & 15);
        u16x4 mtv;
#pragma unroll
        for (int reg = 0; reg < 4; ++reg) {
            const int t = tbase + reg;
            const float dec = __expf(gcs[t] - gcs[i]);
            const float mv = (i <= t) ? dec * aQK[nt][reg] : 0.f;
            *(u16*)((char*)CHM + (size_t)bhc * 8192 + swz64(t, i)) = f2bf(mv);
            const float a = (i < t) ? betal[t] * dec * aKK[nt][reg] : 0.f;
            am[nt][reg] = -a;
            const u16 amb = f2bf(-a);
            *(u16*)((char*)Mim + swz64(t, i)) = amb;
            mtv[reg] = amb;
        }
        *(u16x4*)((char*)MTim + i * 128 + ((((tbase >> 3) ^ (i & 7)) << 4) + (tbase & 7) * 2)) = mtv;
    }
    for (int e = tid; e < 4096; e += 256) {
        const int r = e >> 6, c = e & 63;
        const int ib = swz64(r, c);
        const float qv = bf2f(*(const u16*)((const char*)Ql + ib)) * egcs[r];
        *(u16*)((char*)CHQc + (size_t)bhc * 8192 + ib) = f2bf(qv);
        const float kv = bf2f(*(const u16*)((const char*)Kl + ib));
        const int ob = swz64(c, r);
        *(u16*)((char*)KT1b + ob) = f2bf(kv * bkc[r]);
        *(u16*)((char*)KcTl + ob) = f2bf(kv * egcsC[r]);
    }
    if (tid == 0) CHcC[bhc] = egcs[63];
    __syncthreads();   // Ql/Kl dead; Tl overlay becomes safe

    // ---- phase 2b: T0 = I - A (fp32 master + bf16 image, own rows)
#pragma unroll
    for (int nt = 0; nt < 4; ++nt)
#pragma unroll
        for (int reg = 0; reg < 4; ++reg) {
            const int t = tbase + reg;
            const int i = nt * 16 + (lane & 15);
            const float tv = (t == i) ? 1.f : am[nt][reg];
            Tl[t * 64 + i] = tv;
            *(u16*)((char*)Tb + swz64(t, i)) = f2bf(tv);
        }
    __syncthreads();

    // ---- phase 3: doubling. stage j: M <- M^2 (in place), then T <- T + T*M.
    const int hi = wave * 16 + 15;
#pragma unroll
    for (int j = 1; j <= 5; ++j) {
        f32x4 aM[4] = {};
#pragma unroll
        for (int nt = 0; nt < 4; ++nt) {
            if (nt * 16 > hi - (1 << j)) continue;
#pragma unroll
            for (int kk = 0; kk < 2; ++kk) {
                if (kk * 32 > hi) break;
                aM[nt] = __builtin_amdgcn_mfma_f32_16x16x32_bf16(
                    frag64(Mim, wave * 16, lane, kk), frag64(MTim, nt * 16, lane, kk), aM[nt], 0, 0, 0);
            }
        }
        __syncthreads();
#pragma unroll
        for (int nt = 0; nt < 4; ++nt) {
            const int i = nt * 16 + (lane & 15);
            u16x4 mtv;
#pragma unroll
            for (int reg = 0; reg < 4; ++reg) {
                const int t = tbase + reg;
                const float mv = (t - i >= (1 << j)) ? aM[nt][reg] : 0.f;
                const u16 mb = f2bf(mv);
                *(u16*)((char*)Mim + swz64(t, i)) = mb;
                mtv[reg] = mb;
            }
            *(u16x4*)((char*)MTim + i * 128 + ((((tbase >> 3) ^ (i & 7)) << 4) + (tbase & 7) * 2)) = mtv;
        }
        __syncthreads();
        f32x4 aT[4];
#pragma unroll
        for (int nt = 0; nt < 4; ++nt)
#pragma unroll
            for (int reg = 0; reg < 4; ++reg)
                aT[nt][reg] = Tl[(tbase + reg) * 64 + nt * 16 + (lane & 15)];
#pragma unroll
        for (int nt = 0; nt < 4; ++nt) {
            if (nt * 16 > hi - (1 << j)) continue;
#pragma unroll
            for (int kk = 0; kk < 2; ++kk) {
                if (kk * 32 > hi) break;
                aT[nt] = __builtin_amdgcn_mfma_f32_16x16x32_bf16(
                    frag64(Tb, wave * 16, lane, kk), frag64(MTim, nt * 16, lane, kk), aT[nt], 0, 0, 0);
            }
        }
#pragma unroll
        for (int nt = 0; nt < 4; ++nt)
#pragma unroll
            for (int reg = 0; reg < 4; ++reg) {
                const int t = tbase + reg;
                const int i = nt * 16 + (lane & 15);
                Tl[t * 64 + i] = aT[nt][reg];
                *(u16*)((char*)Tb + swz64(t, i)) = f2bf(aT[nt][reg]);
            }
    }
    __syncthreads();   // doubling done; Tb final; Kl/Mim/MTim reusable

    u16* WTl  = Kl;
    u16* U0Tl = Mim;   // 16KB spans Mim+MTim

    // W = T @ (beta*c*K); write CHW + local W^T image
    {
        f32x4 aW[4] = {};
#pragma unroll
        for (int nt = 0; nt < 4; ++nt)
#pragma unroll
            for (int kk = 0; kk < 2; ++kk) {
                if (kk * 32 > hi) break;
                aW[nt] = __builtin_amdgcn_mfma_f32_16x16x32_bf16(
                    frag64(Tb, wave * 16, lane, kk), frag64(KT1b, nt * 16, lane, kk), aW[nt], 0, 0, 0);
            }
#pragma unroll
        for (int nt = 0; nt < 4; ++nt) {
            const int c = nt * 16 + (lane & 15);
            u16x4 wtv;
#pragma unroll
            for (int reg = 0; reg < 4; ++reg) {
                const int r = tbase + reg;
                const u16 wv = f2bf(aW[nt][reg]);
                *(u16*)((char*)CHW + (size_t)bhc * 8192 + swz64(r, c)) = wv;
                wtv[reg] = wv;
            }
            *(u16x4*)((char*)WTl + c * 128 + ((((tbase >> 3) ^ (c & 7)) << 4) + (tbase & 7) * 2)) = wtv;
        }
    }
    // U0T = (beta*V)^T @ T^T; write CHU0T + local image
#pragma unroll
    for (int rt = 0; rt < 2; ++rt) {
        f32x4 aU[4] = {};
        const int rb = (wave * 2 + rt) * 16;
#pragma unroll
        for (int nt = 0; nt < 4; ++nt)
#pragma unroll
            for (int kk = 0; kk < 2; ++kk) {
                if (kk * 32 > nt * 16 + 15) continue;
                aU[nt] = __builtin_amdgcn_mfma_f32_16x16x32_bf16(
                    frag64(VTb, rb, lane, kk), frag64(Tb, nt * 16, lane, kk), aU[nt], 0, 0, 0);
            }
#pragma unroll
        for (int nt = 0; nt < 4; ++nt)
#pragma unroll
            for (int reg = 0; reg < 4; ++reg) {
                const int dv = rb + ((lane >> 4) << 2) + reg;
                const int c = nt * 16 + (lane & 15);
                const u16 uv = f2bf(aU[nt][reg]);
                *(u16*)((char*)CHU0T + (size_t)bhc * 16384 + swz64(dv, c)) = uv;
                *(u16*)((char*)U0Tl + swz64(dv, c)) = uv;
            }
    }
    __syncthreads();   // WTl/U0Tl ready (KcTl was ready since phase 2a)

    // A2m = -(W^T · Kc^T): out [k][dk], store transposed+negated at [dk][k] (vectorized)
    {
        f32x4 aA[4] = {};
#pragma unroll
        for (int nt = 0; nt < 4; ++nt)
#pragma unroll
            for (int kk = 0; kk < 2; ++kk)
                aA[nt] = __builtin_amdgcn_mfma_f32_16x16x32_bf16(
                    frag64(WTl, wave * 16, lane, kk), frag64(KcTl, nt * 16, lane, kk), aA[nt], 0, 0, 0);
#pragma unroll
        for (int nt = 0; nt < 4; ++nt) {
            const int dk = nt * 16 + (lane & 15);
            u16x4 av;
#pragma unroll
            for (int reg = 0; reg < 4; ++reg) av[reg] = f2bf(-aA[nt][reg]);
            *(u16x4*)((char*)CHA2m + (size_t)bhc * 8192 + dk * 128 +
                      ((((tbase >> 3) ^ (dk & 7)) << 4) + (tbase & 7) * 2)) = av;
        }
    }
    // B = U0T · Kc^T: out [dv][dk]
#pragma unroll
    for (int rt = 0; rt < 2; ++rt) {
        f32x4 aB[4] = {};
        const int rb = (wave * 2 + rt) * 16;
#pragma unroll
        for (int nt = 0; nt < 4; ++nt)
#pragma unroll
            for (int kk = 0; kk < 2; ++kk)
                aB[nt] = __builtin_amdgcn_mfma_f32_16x16x32_bf16(
                    frag64(U0Tl, rb, lane, kk), frag64(KcTl, nt * 16, lane, kk), aB[nt], 0, 0, 0);
#pragma unroll
        for (int nt = 0; nt < 4; ++nt)
#pragma unroll
            for (int reg = 0; reg < 4; ++reg) {
                const int dv = rb + ((lane >> 4) << 2) + reg;
                const int dk = nt * 16 + (lane & 15);
                *(u16*)((char*)CHB + (size_t)bhc * 16384 + swz64(dv, dk)) = f2bf(aB[nt][reg]);
            }
    }
}

// ---------------- scan stage 2: minimal sequential recurrence S' = cC*S + S*A2m + B; exports S0
__global__ __launch_bounds__(256) void k_scan2(
    const u16* __restrict__ CHA2m, const u16* __restrict__ CHB,
    const float* __restrict__ CHcC, u16* __restrict__ CHS0) {
    __shared__ __align__(16) u16 stg[2][8192];   // per buf: A2m 8KB | B(dvh) 8KB
    __shared__ __align__(16) u16 STb[4096];
    __shared__ float ST[64 * 66];
    const int blk = blockIdx.x;
    const int bb = blk >> 5, h = (blk >> 1) & 15, dvh = blk & 1;
    const int bh = bb * 16 + h;
    const int tid = threadIdx.x, lane = tid & 63, wave = tid >> 6;

    for (int e = tid; e < 64 * 66; e += 256) ST[e] = 0.f;
    for (int e = tid; e < 4096; e += 256) STb[e] = 0;

    auto stage = [&](int buf, int ch) {
        const size_t base = (size_t)(bh * 16 + ch);
        const u16* sA = CHA2m + base * 4096;
        const u16* sB = CHB + base * 8192 + dvh * 4096;
#pragma unroll
        for (int r = 0; r < 2; ++r) {
            const int g = r * 256 + tid;
            async16(sA + (size_t)g * 8, &stg[buf][g * 8]);
            async16(sB + (size_t)g * 8, &stg[buf][4096 + g * 8]);
        }
    };
    stage(0, 0);
    int cur = 0;
    for (int ch = 0; ch < 16; ++ch) {
        asm volatile("s_waitcnt vmcnt(0)" ::: "memory");
        __syncthreads();
        if (ch < 15) stage(cur ^ 1, ch + 1);
        const u16* sA2 = &stg[cur][0];
        const u16* sB = &stg[cur][4096];
        f32x4 acc[4] = {};
#pragma unroll
        for (int nt = 0; nt < 4; ++nt)
#pragma unroll
            for (int kk = 0; kk < 2; ++kk)
                acc[nt] = __builtin_amdgcn_mfma_f32_16x16x32_bf16(
                    frag64(STb, wave * 16, lane, kk), frag64(sA2, nt * 16, lane, kk), acc[nt], 0, 0, 0);
        const float cC = CHcC[bh * 16 + ch];
        const size_t sbase = ((size_t)(bh * 16 + ch + 1) * 2 + dvh) * 8192;
#pragma unroll
        for (int nt = 0; nt < 4; ++nt)
#pragma unroll
            for (int reg = 0; reg < 4; ++reg) {
                const int rr = wave * 16 + ((lane >> 4) << 2) + reg;
                const int cc = nt * 16 + (lane & 15);
                const float bv = bf2f(*(const u16*)((const char*)sB + swz64(rr, cc)));
                const float ns = cC * ST[rr * 66 + cc] + acc[nt][reg] + bv;
                ST[rr * 66 + cc] = ns;
                const u16 nb = f2bf(ns);
                *(u16*)((char*)STb + swz64(rr, cc)) = nb;
                if (ch < 15) *(u16*)((char*)CHS0 + sbase + swz64(rr, cc)) = nb;
            }
        cur ^= 1;
    }
}

// ---------------- scan stage 3 (fully parallel): u = U0T - S0*W^T; O = M@u + Qc@S0;
// fused per-head RMSNorm * gate -> OG
__global__ __launch_bounds__(256) void k_scan3(
    const u16* __restrict__ CHM, const u16* __restrict__ CHQc, const u16* __restrict__ CHW,
    const u16* __restrict__ CHU0T, const u16* __restrict__ CHS0, const u16* __restrict__ P,
    const float* __restrict__ onw, u16* __restrict__ OG) {
    __shared__ __align__(16) char sm3[73728];
    u16* sM  = (u16*)sm3;                 // 8KB
    u16* sQc = (u16*)(sm3 + 8192);        // 8KB
    u16* sW  = (u16*)(sm3 + 16384);       // 8KB
    u16* sU  = (u16*)(sm3 + 24576);       // 16KB U0T -> u (in place)
    u16* sS0 = (u16*)(sm3 + 40960);       // 16KB
    u16* sPg = (u16*)(sm3 + 57344);       // 16KB gate tile [64][128]
    const int blk = blockIdx.x;           // bb*256 + h*16 + ch
    const int bb = blk >> 8, h = (blk >> 4) & 15, ch = blk & 15;
    const size_t bhc = blk;
    const int tid = threadIdx.x, lane = tid & 63, wave = tid >> 6;
    const bool hasS0 = (ch != 0);

#pragma unroll
    for (int r = 0; r < 2; ++r) {
        const int g = r * 256 + tid;
        async16(CHM + bhc * 4096 + (size_t)g * 8, sM + g * 8);
        async16(CHQc + bhc * 4096 + (size_t)g * 8, sQc + g * 8);
        async16(CHW + bhc * 4096 + (size_t)g * 8, sW + g * 8);
#pragma unroll
        for (int d = 0; d < 2; ++d) {
            async16(CHU0T + (bhc * 2 + d) * 4096 + (size_t)g * 8, sU + d * 4096 + g * 8);
            if (hasS0)
                async16(CHS0 + (bhc * 2 + d) * 4096 + (size_t)g * 8, sS0 + d * 4096 + g * 8);
        }
    }
    const long prow0 = ((long)bb * 1024 + ch * 64) * N1P + 4128 + h * 128;
#pragma unroll
    for (int k = 0; k < 4; ++k) {
        const int i = tid + k * 256;
        const int row = i >> 4, seg = i & 15;
        async16(P + prow0 + (long)row * N1P + seg * 8, sPg + i * 8);
    }
    asm volatile("s_waitcnt vmcnt(0)" ::: "memory");
    __syncthreads();

    if (hasS0) {
        // u = U0T - S0 * W^T (in place, own rows)
#pragma unroll
        for (int d = 0; d < 2; ++d) {
            f32x4 au[4] = {};
#pragma unroll
            for (int nt = 0; nt < 4; ++nt)
#pragma unroll
                for (int kk = 0; kk < 2; ++kk)
                    au[nt] = __builtin_amdgcn_mfma_f32_16x16x32_bf16(
                        frag64(sS0 + d * 4096, wave * 16, lane, kk), frag64(sW, nt * 16, lane, kk),
                        au[nt], 0, 0, 0);
#pragma unroll
            for (int nt = 0; nt < 4; ++nt)
#pragma unroll
                for (int reg = 0; reg < 4; ++reg) {
                    const int dv = wave * 16 + ((lane >> 4) << 2) + reg;
                    const int c = nt * 16 + (lane & 15);
                    u16* p = (u16*)((char*)sU + d * 8192 + swz64(dv, c));
                    *p = f2bf(bf2f(*p) - au[nt][reg]);
                }
        }
        __syncthreads();
    }

    f32x4 accO[2][4] = {};
#pragma unroll
    for (int d = 0; d < 2; ++d)
#pragma unroll
        for (int nt = 0; nt < 4; ++nt)
#pragma unroll
            for (int kk = 0; kk < 2; ++kk) {
                accO[d][nt] = __builtin_amdgcn_mfma_f32_16x16x32_bf16(
                    frag64(sM, wave * 16, lane, kk), frag64(sU + d * 4096, nt * 16, lane, kk),
                    accO[d][nt], 0, 0, 0);
                if (hasS0)
                    accO[d][nt] = __builtin_amdgcn_mfma_f32_16x16x32_bf16(
                        frag64(sQc, wave * 16, lane, kk), frag64(sS0 + d * 4096, nt * 16, lane, kk),
                        accO[d][nt], 0, 0, 0);
            }

    const int rsub = (lane >> 4) * 4, csub = lane & 15;
    float rn[4];
#pragma unroll
    for (int reg = 0; reg < 4; ++reg) {
        float ss = 0.f;
#pragma unroll
        for (int d = 0; d < 2; ++d)
#pragma unroll
            for (int nt = 0; nt < 4; ++nt) {
                const float v = accO[d][nt][reg];
                ss += v * v;
            }
        ss += __shfl_xor(ss, 1); ss += __shfl_xor(ss, 2);
        ss += __shfl_xor(ss, 4); ss += __shfl_xor(ss, 8);
        rn[reg] = rsqrtf(ss * (1.f / 128.f) + 1e-6f);
    }
    __syncthreads();   // done reading sM/sQc/sW/sU/sS0 -> reuse as out tile
    u16* ct = (u16*)sm3;   // [64][136]
#pragma unroll
    for (int d = 0; d < 2; ++d)
#pragma unroll
        for (int nt = 0; nt < 4; ++nt)
#pragma unroll
            for (int reg = 0; reg < 4; ++reg) {
                const int rr = wave * 16 + rsub + reg;
                const int dv = d * 64 + nt * 16 + csub;
                const float g = bf2f(sPg[rr * 128 + dv]);
                const float val = accO[d][nt][reg] * rn[reg] * onw[dv] * g * sigm(g);
                ct[rr * 136 + dv] = f2bf(val);
            }
    __syncthreads();
#pragma unroll
    for (int k = 0; k < 4; ++k) {
        const int f = (tid + k * 256) * 8;
        const int r2 = f >> 7, c = f & 127;
        *(u16x8*)&OG[(size_t)(bb * 1024 + ch * 64 + r2) * 2048 + h * 128 + c] =
            *(const u16x8*)&ct[r2 * 136 + c];
    }
}

extern "C" void kernel_launch(void* const* d_in, const int* in_sizes, int n_in,
                              void* d_out, int out_size, void* d_ws, size_t ws_size,
                              hipStream_t stream) {
    const float* x   = (const float*)d_in[0];
    const float* n1w = (const float*)d_in[1];
    const float* wq  = (const float*)d_in[2];
    const float* wk  = (const float*)d_in[3];
    const float* wv  = (const float*)d_in[4];
    const float* cq  = (const float*)d_in[5];
    const float* ck  = (const float*)d_in[6];
    const float* cv  = (const float*)d_in[7];
    const float* wb  = (const float*)d_in[8];
    const float* wa  = (const float*)d_in[9];
    const float* Alg = (const float*)d_in[10];
    const float* dtb = (const float*)d_in[11];
    const float* wg  = (const float*)d_in[12];
    const float* onw = (const float*)d_in[13];
    const float* wo  = (const float*)d_in[14];
    const float* n2w = (const float*)d_in[15];
    const float* w1  = (const float*)d_in[16];
    const float* w2  = (const float*)d_in[17];
    const float* w3  = (const float*)d_in[18];

    if (ws_size < 132384768ULL) return;

    char* ws = (char*)d_ws;
    u16*   WcatT = (u16*)(ws + 0);            // [6400][1024] bf16 (CHW/CHM/CHQc reuse)
    u16*   WoT   = (u16*)(ws + 13107200);     // [1024][2048]
    u16*   W13T  = (u16*)(ws + 17301504);     // [5632][1024] group-16 interleaved w1/w3
    u16*   W2T   = (u16*)(ws + 28835840);     // [1024][2816]
    u16*   hA    = (u16*)(ws + 34603008);     // [2048][1024] (h2A reuse)
    u16*   P     = (u16*)(ws + 38797312);     // [2048][6400]
    u16*   Mm    = (u16*)(ws + 65011712);     // [2048][2816] bf16 MLP intermediate
    u16*   OG    = (u16*)(ws + 73400320);     // [2048][2048] bf16
    float* X2    = (float*)(ws + 82051072);   // [2048][1024] fp32
    u16*   CHU0T = (u16*)(ws + 103022592);    // [512][128][64] bf16 image
    float* CHcC  = (float*)(ws + 111411200);  // [512]
    u16*   CHA2m = (u16*)(ws + 111413248);    // [512][64][64] bf16 image (-W^T Kc^T, transposed)
    u16*   CHB   = (u16*)(ws + 115607552);    // [512][128][64] bf16 image (U0T Kc^T)
    u16*   CHS0  = (u16*)(ws + 123996160);    // [512*2][64][64] bf16 image per dvh
    u16*   CHW   = WcatT;                     // [512][64][64] image
    u16*   CHM   = (u16*)(ws + 4194304);
    u16*   CHQc  = (u16*)(ws + 8388608);
    u16*   h2A = hA;

    // fused weight transposes (fp32 [K][N] -> bf16 [N][K]) + rmsnorm-1; tiles 64k x 32n
    TJobs tj;
    tj.j[0] = { wq, WcatT, 1024, 1024,    0, 1, 1024,     0, 32, 0 };   // 512
    tj.j[1] = { wk, WcatT, 1024, 1024, 1024, 1, 1024,   512, 32, 0 };   // 512
    tj.j[2] = { wv, WcatT, 1024, 2048, 2048, 1, 2048,  1024, 64, 0 };   // 1024
    tj.j[3] = { wb, WcatT, 1024,   16, 4096, 1,   16,  2048,  1, 0 };   // 16
    tj.j[4] = { wa, WcatT, 1024,   16, 4112, 1,   16,  2064,  1, 0 };   // 16
    tj.j[5] = { wg, WcatT, 1024, 2048, 4128, 1, 2272,  2080, 71, 0 };   // 1136 (pads rows to 6400)
    tj.j[6] = { wo, WoT,   2048, 1024,    0, 1, 1024,  3216, 32, 0 };   // 1024
    tj.j[7] = { w1, W13T,  1024, 2816,    0, 1, 2816,  4240, 88, 1 };   // 1408 group-16 even
    tj.j[8] = { w3, W13T,  1024, 2816,   16, 1, 2816,  5648, 88, 1 };   // 1408 group-16 odd
    tj.j[9] = { w2, W2T,   2816, 1024,    0, 1, 1024,  7056, 32, 0 };   // 1408 -> blkBase end 8464
    k_transpose_all<<<8464 + 2048, 256, 0, stream>>>(tj, 10, 8464, x, n1w, hA);

    k_gemm256<2><<<200, 512, 0, stream>>>(hA, WcatT, P, N1P, 1024);

    k_scan1<<<512, 256, 0, stream>>>(P, cq, ck, cv, Alg, dtb, CHW, CHM, CHQc, CHU0T,
                                     CHcC, CHA2m, CHB);
    k_scan2<<<64, 256, 0, stream>>>(CHA2m, CHB, CHcC, CHS0);
    k_scan3<<<512, 256, 0, stream>>>(CHM, CHQc, CHW, CHU0T, CHS0, P, onw, OG);

    k_gemm_skinny<<<256, 512, 0, stream>>>(OG, WoT, X2, x, 1024, 2048);

    k_rmsnorm<<<2048, 256, 0, stream>>>(X2, n2w, h2A);
    k_gemm256<3><<<176, 512, 0, stream>>>(h2A, W13T, Mm, 2816, 1024);  // fused silu(u1)*u3
    k_gemm_skinny<<<256, 512, 0, stream>>>(Mm, W2T, (float*)d_out, X2, 1024, 2816);
}

// Round 19
// 209.224 us; speedup vs baseline: 1.0983x; 1.0349x over previous
//
#include <hip/hip_runtime.h>
#include <stdint.h>

typedef unsigned short u16;
typedef float f32x4 __attribute__((ext_vector_type(4)));
typedef __bf16 bf16x8 __attribute__((ext_vector_type(8)));
typedef unsigned short u16x8 __attribute__((ext_vector_type(8)));
typedef unsigned short u16x4 __attribute__((ext_vector_type(4)));

#define N1P 6400   // padded concat width: q(1024)|k(1024)|v(2048)|b(16)|a(16)|g(2048)|pad(224)

__device__ __forceinline__ u16 f2bf(float f) {
    union { float f; uint32_t u; } v; v.f = f;
    uint32_t u = v.u;
    return (u16)((u + 0x7FFFu + ((u >> 16) & 1u)) >> 16);
}
__device__ __forceinline__ float bf2f(u16 h) {
    union { uint32_t u; float f; } v; v.u = ((uint32_t)h) << 16; return v.f;
}
__device__ __forceinline__ float sigm(float x) { return 1.f / (1.f + __expf(-x)); }

__device__ __forceinline__ void async16(const u16* g, u16* l) {
    __builtin_amdgcn_global_load_lds((const __attribute__((address_space(1))) void*)g,
                                     (__attribute__((address_space(3))) void*)l, 16, 0, 0);
}

// byte offset inside a [R][64] bf16 "swizzled image": 16B units XOR'd with row&7
__device__ __forceinline__ int swz64(int row, int col) {
    return row * 128 + ((((col >> 3) ^ (row & 7)) << 3) + (col & 7)) * 2;
}
// MFMA fragment read from a swizzled [R][64] bf16 image (rows rowbase..rowbase+15, K-offset kk*32)
__device__ __forceinline__ bf16x8 frag64(const u16* m, int rowbase, int lane, int kk) {
    const int row = rowbase + (lane & 15);
    const int unit = (lane >> 4) + (kk << 2);
    return *(const bf16x8*)((const char*)m + row * 128 + ((unit ^ (row & 7)) << 4));
}

// ---------------- fused transpose + fp32->bf16 convert (10 weights) + rmsnorm-1 (one launch)
// Transpose tile: 64(k) x 32(n); writes one u16x8 per thread.
// mode 0: dst row = rowOff + n*rowStride ; mode 1: dst row = rowOff + (n>>4)*32 + (n&15)
struct TJob { const float* src; u16* dst; int rows, cols, rowOff, rowStride, nOut, blkBase, gx, mode; };
struct TJobs { TJob j[10]; };

__global__ __launch_bounds__(256) void k_transpose_all(TJobs jobs, int njobs, int rmsBase,
                                                       const float* __restrict__ xin,
                                                       const float* __restrict__ n1w,
                                                       u16* __restrict__ hOut) {
    __shared__ float tile[64][33];
    const int bid = blockIdx.x;
    const int tid = threadIdx.x;
    if (bid >= rmsBase) {
        // ---- rmsnorm row (D=1024, fp32 -> bf16)
        const int row = bid - rmsBase;
        const int lane = tid & 63, wave = tid >> 6;
        const float4 v = ((const float4*)(xin + (size_t)row * 1024))[tid];
        float ss = v.x * v.x + v.y * v.y + v.z * v.z + v.w * v.w;
#pragma unroll
        for (int o = 1; o < 64; o <<= 1) ss += __shfl_xor(ss, o);
        float* sred = &tile[0][0];
        if (lane == 0) sred[wave] = ss;
        __syncthreads();
        const float tot = sred[0] + sred[1] + sred[2] + sred[3];
        const float rn = rsqrtf(tot * (1.f / 1024.f) + 1e-6f);
        const float4 wv = ((const float4*)n1w)[tid];
        uint2 pk;
        pk.x = (uint32_t)f2bf(v.x * rn * wv.x) | ((uint32_t)f2bf(v.y * rn * wv.y) << 16);
        pk.y = (uint32_t)f2bf(v.z * rn * wv.z) | ((uint32_t)f2bf(v.w * rn * wv.w) << 16);
        *(uint2*)&hOut[(size_t)row * 1024 + tid * 4] = pk;
        return;
    }
    int ji = 0;
#pragma unroll
    for (int i = 1; i < 10; ++i)
        if (i < njobs && bid >= jobs.j[i].blkBase) ji = i;
    const TJob J = jobs.j[ji];
    const int bx = bid - J.blkBase;
    const int n0 = (bx % J.gx) * 32, k0 = (bx / J.gx) * 64;
    const int tx = tid & 31, ty = tid >> 5;      // 32 x 8
    const int c = n0 + tx;
    const bool cok = (c < J.cols);
#pragma unroll
    for (int i = 0; i < 8; ++i) {
        const int r = k0 + i * 8 + ty;           // rows are multiples of 64 -> always in range
        tile[i * 8 + ty][tx] = cok ? J.src[(size_t)r * J.cols + c] : 0.f;
    }
    __syncthreads();
    const int n = tid >> 3, seg = tid & 7;
    const int ng = n0 + n;
    if (ng < J.nOut) {
        u16x8 o;
#pragma unroll
        for (int e = 0; e < 8; ++e) o[e] = f2bf(tile[seg * 8 + e][n]);
        const int drow = (J.mode == 0) ? (J.rowOff + ng * J.rowStride)
                                       : (J.rowOff + ((ng >> 4) << 5) + (ng & 15));
        *(u16x8*)&J.dst[(size_t)drow * J.rows + k0 + seg * 8] = o;
    }
}

// ---------------- rmsnorm over D=1024, fp32 in -> bf16 out (used for norm-2 only)
__global__ __launch_bounds__(256) void k_rmsnorm(const float* __restrict__ x, const float* __restrict__ w,
                                                 u16* __restrict__ out) {
    const int row = blockIdx.x, tid = threadIdx.x, lane = tid & 63, wave = tid >> 6;
    const float4 v = ((const float4*)(x + (size_t)row * 1024))[tid];
    float ss = v.x * v.x + v.y * v.y + v.z * v.z + v.w * v.w;
#pragma unroll
    for (int o = 1; o < 64; o <<= 1) ss += __shfl_xor(ss, o);
    __shared__ float sred[4];
    if (lane == 0) sred[wave] = ss;
    __syncthreads();
    const float tot = sred[0] + sred[1] + sred[2] + sred[3];
    const float rn = rsqrtf(tot * (1.f / 1024.f) + 1e-6f);
    const float4 wv = ((const float4*)w)[tid];
    uint2 pk;
    pk.x = (uint32_t)f2bf(v.x * rn * wv.x) | ((uint32_t)f2bf(v.y * rn * wv.y) << 16);
    pk.y = (uint32_t)f2bf(v.z * rn * wv.z) | ((uint32_t)f2bf(v.w * rn * wv.w) << 16);
    *(uint2*)&out[(size_t)row * 1024 + tid * 4] = pk;
}

// ---------------- 256x256 8-phase GEMM (T2+T3+T4+T5), BK=64, 8 waves (2Mx4N), wave tile 128x64.
// A[2048][Kd] bf16 row-major, Bt[N'][Kd] bf16 row-major. Kd must be multiple of 128.
// EPI 2 = bf16 store (width N); EPI 3 = fused silu(u1)*u3, B group-16-interleaved (out width N)
template <int EPI>
__global__ __launch_bounds__(512, 2) void k_gemm256(const u16* __restrict__ A, const u16* __restrict__ Bt,
                                                    u16* __restrict__ Cout, int N, int Kd) {
    __shared__ __align__(16) u16 L[65536];   // 128KB: buf{0,1} x (A 256x64 | B 256x64) swizzled images
    const int q8 = (int)gridDim.x >> 3;
    const int bid = blockIdx.x;
    const int wg = (bid & 7) * q8 + (bid >> 3);      // XCD-contiguous
    const int bm = wg & 7, bn = wg >> 3;             // M blocks = 2048/256 = 8
    const int tid = threadIdx.x, lane = tid & 63, wave = tid >> 6;
    const int wm = wave >> 2, wn = wave & 3;         // 2 x 4 wave grid

    const int scol = ((tid & 7) ^ ((tid >> 3) & 7)) * 8;  // pre-swizzled source granule
    const u16* gA = A + (size_t)(bm * 256 + (tid >> 3)) * Kd + scol;
    const u16* gB = Bt + (size_t)(bn * 256 + (tid >> 3)) * Kd + scol;
    u16* dstT = L + tid * 8;

    const int NT = Kd >> 6;
    const int NI = NT >> 1;

    auto issue = [&](const u16* g, int mtx, int kt, int h) {   // one half-tile = 2 gloads/thread
        u16* d = dstT + (kt & 1) * 32768 + mtx * 16384 + h * 8192;
        const u16* s = g + (size_t)(h * 128) * Kd + kt * 64;
        async16(s, d);
        async16(s + (size_t)64 * Kd, d + 4096);
    };

    issue(gB, 1, 0, 0); issue(gB, 1, 0, 1);
    issue(gA, 0, 0, 0); issue(gA, 0, 0, 1);
    issue(gB, 1, 1, 0); issue(gB, 1, 1, 1);
    asm volatile("s_waitcnt vmcnt(4)" ::: "memory");   // tile0 landed
    __builtin_amdgcn_s_barrier();

    f32x4 acc[8][4] = {};
    bf16x8 bq[4][2];

    for (int i = 0; i < NI; ++i) {
        const int kt0 = 2 * i;
#pragma unroll
        for (int p = 0; p < 8; ++p) {
            const int half = p >> 2;
            const int q = p & 3;
            const u16* Ab = L + half * 32768;
            const u16* Bb = L + half * 32768 + 16384;
            if (q == 0) {
#pragma unroll
                for (int ni = 0; ni < 4; ++ni)
#pragma unroll
                    for (int kk = 0; kk < 2; ++kk)
                        bq[ni][kk] = frag64(Bb, wn * 64 + ni * 16, lane, kk);
            }
            bf16x8 af[2][2];
#pragma unroll
            for (int j = 0; j < 2; ++j)
#pragma unroll
                for (int kk = 0; kk < 2; ++kk)
                    af[j][kk] = frag64(Ab, wm * 128 + (2 * q + j) * 16, lane, kk);
            if (p == 0) { if (kt0 + 1 < NT) issue(gA, 0, kt0 + 1, 0); }
            if (p == 1) { if (kt0 + 1 < NT) issue(gA, 0, kt0 + 1, 1);
                          if (kt0 + 2 < NT) issue(gB, 1, kt0 + 2, 0); }
            if (p == 2) { if (kt0 + 2 < NT) issue(gB, 1, kt0 + 2, 1); }
            if (p == 4) { if (kt0 + 2 < NT) issue(gA, 0, kt0 + 2, 0); }
            if (p == 5) { if (kt0 + 2 < NT) issue(gA, 0, kt0 + 2, 1);
                          if (kt0 + 3 < NT) issue(gB, 1, kt0 + 3, 0); }
            if (p == 6) { if (kt0 + 3 < NT) issue(gB, 1, kt0 + 3, 1); }
            if (p == 3) { if (i + 1 < NI) { asm volatile("s_waitcnt vmcnt(4)" ::: "memory"); }
                          else            { asm volatile("s_waitcnt vmcnt(0)" ::: "memory"); } }
            if (p == 7) { if (i + 1 < NI) { asm volatile("s_waitcnt vmcnt(4)" ::: "memory"); } }
            __builtin_amdgcn_s_barrier();
            __builtin_amdgcn_s_setprio(1);
#pragma unroll
            for (int j = 0; j < 2; ++j)
#pragma unroll
                for (int ni = 0; ni < 4; ++ni)
#pragma unroll
                    for (int kk = 0; kk < 2; ++kk)
                        acc[2 * q + j][ni] = __builtin_amdgcn_mfma_f32_16x16x32_bf16(
                            af[j][kk], bq[ni][kk], acc[2 * q + j][ni], 0, 0, 0);
            __builtin_amdgcn_s_setprio(0);
            __builtin_amdgcn_s_barrier();
        }
    }

    const int rsub = (lane >> 4) * 4, csub = lane & 15;
    if constexpr (EPI == 2) {
        u16* ct = L;                                 // [128][264] staged per wm-round
#pragma unroll
        for (int r = 0; r < 2; ++r) {
            if (wm == r) {
#pragma unroll
                for (int mi = 0; mi < 8; ++mi)
#pragma unroll
                    for (int ni = 0; ni < 4; ++ni)
#pragma unroll
                        for (int rr = 0; rr < 4; ++rr)
                            ct[(mi * 16 + rsub + rr) * 264 + wn * 64 + ni * 16 + csub] =
                                f2bf(acc[mi][ni][rr]);
            }
            __syncthreads();
#pragma unroll
            for (int k = 0; k < 8; ++k) {
                const int f = (tid + k * 512) * 8;
                const int r2 = f >> 8, c = f & 255;
                *(u16x8*)&Cout[(size_t)(bm * 256 + r * 128 + r2) * N + bn * 256 + c] =
                    *(const u16x8*)&ct[r2 * 264 + c];
            }
            __syncthreads();
        }
    } else {
        u16* ct = L;                                 // [256][132]
#pragma unroll
        for (int mi = 0; mi < 8; ++mi)
#pragma unroll
            for (int g = 0; g < 2; ++g)
#pragma unroll
                for (int rr = 0; rr < 4; ++rr) {
                    const float u1 = acc[mi][2 * g][rr];
                    const float u3 = acc[mi][2 * g + 1][rr];
                    ct[(wm * 128 + mi * 16 + rsub + rr) * 132 + wn * 32 + g * 16 + csub] =
                        f2bf(u1 * sigm(u1) * u3);
                }
        __syncthreads();
#pragma unroll
        for (int k = 0; k < 8; ++k) {
            const int f = (tid + k * 512) * 8;
            const int r2 = f >> 7, c = f & 127;
            *(u16x8*)&Cout[(size_t)(bm * 256 + r2) * N + bn * 128 + c] =
                *(const u16x8*)&ct[r2 * 132 + c];
        }
    }
}

// ---------------- 2-phase bf16 GEMM (skinny N=1024): tile 64(M)x64(N), 4 waves (2Mx2N), dbuf,
// grid 512 = 2 blocks/CU (cross-block overlap hides the vmcnt/barrier drain).
// bn-fastest XCD ordering: each XCD chunk = 16 bn x 4 bm -> B reuse in L2.
__global__ __launch_bounds__(256) void k_gemm_skinny(const u16* __restrict__ A, const u16* __restrict__ Bt,
                                                     float* __restrict__ Cout, const float* __restrict__ Res,
                                                     int N, int Kd) {
    __shared__ __align__(16) char smem[32768];
    u16* Asb = (u16*)smem;                       // [2][64*64]
    u16* Bsb = (u16*)(smem + 16384);             // [2][64*64]
    const int q = (int)gridDim.x >> 3;
    const int bid = blockIdx.x;
    const int wg = (bid & 7) * q + (bid >> 3);   // XCD-contiguous
    const int bn = wg & 15, bm = wg >> 4;        // bn fastest -> B-matrix locality per XCD
    const int tid = threadIdx.x, lane = tid & 63, wave = tid >> 6;
    const int wm = wave >> 1, wn = wave & 1;     // 2 x 2 wave grid, wave tile 32x32

    f32x4 acc[2][2] = {};
    const int NT = Kd >> 6;

    auto stage = [&](int kt, int buf) {          // 4 vmem instructions per wave (2 A + 2 B)
        const int k0 = kt << 6;
        u16* Ab = Asb + buf * 4096;
        u16* Bb = Bsb + buf * 4096;
#pragma unroll
        for (int r = 0; r < 2; ++r) {
            const int row = r * 32 + wave * 8 + (lane >> 3);
            const int sc = (((lane & 7) ^ (row & 7)) << 3);
            async16(A + (size_t)(bm * 64 + row) * Kd + k0 + sc, Ab + r * 2048 + wave * 512);
            async16(Bt + (size_t)(bn * 64 + row) * Kd + k0 + sc, Bb + r * 2048 + wave * 512);
        }
    };

    stage(0, 0);
    asm volatile("s_waitcnt vmcnt(0)" ::: "memory");
    __syncthreads();

    int buf = 0;
    for (int t = 0; t < NT; ++t) {
        if (t + 1 < NT) stage(t + 1, buf ^ 1);   // issue next-tile loads EARLY
        const u16* Ab = Asb + buf * 4096;
        const u16* Bb = Bsb + buf * 4096;
#pragma unroll
        for (int kk = 0; kk < 2; ++kk) {
            bf16x8 af[2], bfr[2];
#pragma unroll
            for (int mi = 0; mi < 2; ++mi) af[mi] = frag64(Ab, wm * 32 + mi * 16, lane, kk);
#pragma unroll
            for (int ni = 0; ni < 2; ++ni) bfr[ni] = frag64(Bb, wn * 32 + ni * 16, lane, kk);
#pragma unroll
            for (int mi = 0; mi < 2; ++mi)
#pragma unroll
                for (int ni = 0; ni < 2; ++ni)
                    acc[mi][ni] = __builtin_amdgcn_mfma_f32_16x16x32_bf16(af[mi], bfr[ni], acc[mi][ni], 0, 0, 0);
        }
        asm volatile("s_waitcnt vmcnt(0)" ::: "memory");   // next tile landed (hidden under MFMA)
        __syncthreads();
        buf ^= 1;
    }

    const int rsub = (lane >> 4) * 4;
    const int csub = lane & 15;
    float* ctile = (float*)smem;                 // [64][68]
#pragma unroll
    for (int mi = 0; mi < 2; ++mi)
#pragma unroll
        for (int ni = 0; ni < 2; ++ni)
#pragma unroll
            for (int r = 0; r < 4; ++r)
                ctile[(wm * 32 + mi * 16 + rsub + r) * 68 + wn * 32 + ni * 16 + csub] = acc[mi][ni][r];
    __syncthreads();
#pragma unroll
    for (int k = 0; k < 4; ++k) {
        const int f = (tid + k * 256) * 4;
        const int r = f >> 6, c = f & 63;
        float4 v = *(const float4*)&ctile[r * 68 + c];
        const float4 rv = *(const float4*)&Res[(size_t)(bm * 64 + r) * N + bn * 64 + c];
        v.x += rv.x; v.y += rv.y; v.z += rv.z; v.w += rv.w;
        *(float4*)&Cout[(size_t)(bm * 64 + r) * N + bn * 64 + c] = v;
    }
}

// ---------------- chunked gated delta rule: stage 1 (per b,h,chunk — fully parallel)
// FUSED conv(4)+silu+l2norm + beta/log-decay; T = (I+A)^{-1} via doubling; exports M, Qc, W,
// U0T and affine-recurrence operands A2m = -(W^T·Kc^T), B = U0T·Kc^T. KcT kept in LDS only.
__global__ __launch_bounds__(256) void k_scan1(
    const u16* __restrict__ P, const float* __restrict__ cwq, const float* __restrict__ cwk,
    const float* __restrict__ cwv, const float* __restrict__ A_log, const float* __restrict__ dtb,
    u16* __restrict__ CHW, u16* __restrict__ CHM, u16* __restrict__ CHQc,
    u16* __restrict__ CHU0T, float* __restrict__ CHcC,
    u16* __restrict__ CHA2m, u16* __restrict__ CHB) {
    __shared__ __align__(16) char sm[75008];
    u16* Ql   = (u16*)(sm);            // 8KB
    u16* Kl   = (u16*)(sm + 8192);     // 8KB   (later: W^T image)
    u16* VTb  = (u16*)(sm + 16384);    // 16KB
    u16* KT1b = (u16*)(sm + 32768);    // 8KB
    u16* Mim  = (u16*)(sm + 40960);    // 8KB   (phase0: Vtmp low;  later: U0T image low)
    u16* MTim = (u16*)(sm + 49152);    // 8KB   (phase0: Vtmp high; later: U0T image high)
    u16* Tb   = (u16*)(sm + 57344);    // 8KB
    u16* KcTl = (u16*)(sm + 65536);    // 8KB   KcT image, LDS-resident
    float* Tl    = (float*)sm;         // 16KB fp32 T master, overlays Ql+Kl after 2a
    float* gcs   = (float*)(sm + 73728);
    float* betal = (float*)(sm + 73984);
    float* egcs  = (float*)(sm + 74240);
    float* egcsC = (float*)(sm + 74496);
    float* bkc   = (float*)(sm + 74752);
    u16* Vtmp = Mim;                   // [64][128] linear conv-v staging (16KB)

    const int blk = blockIdx.x;                      // bb*256 + h*16 + ch
    const int bb = blk >> 8, h = (blk >> 4) & 15, ch = blk & 15;
    const int bhc = blk;
    const int tid = threadIdx.x, lane = tid & 63, wave = tid >> 6;
    const long rowbase = (long)bb * 1024 + ch * 64;
    const int tbase = wave * 16 + ((lane >> 4) << 2);

    // ---- phase 0 (fused conv): beta/log-decay scalars + conv/silu/l2norm into Ql/Kl/Vtmp
    if (tid < 64) {
        const long pr = (rowbase + tid) * (long)N1P;
        betal[tid] = sigm(bf2f(P[pr + 4096 + h]));
        const float a = bf2f(P[pr + 4112 + h]) + dtb[h];
        const float sp = (a > 15.f) ? a : log1pf(__expf(a));
        gcs[tid] = -__expf(A_log[h]) * sp;           // raw log decay (cumsum later)
    }
    {
        const int g = tid & 31, rb2 = tid >> 5;      // col-group of 8, row-block of 8
        int colbase; const float* cw;
        if (g < 8)       { const int cc = h * 64 + g * 8;        colbase = cc;        cw = cwq + cc * 4; }
        else if (g < 16) { const int cc = h * 64 + (g - 8) * 8;   colbase = 1024 + cc; cw = cwk + cc * 4; }
        else             { const int cc = h * 128 + (g - 16) * 8; colbase = 2048 + cc; cw = cwv + cc * 4; }
        float4 wgt[8];
#pragma unroll
        for (int e = 0; e < 8; ++e) wgt[e] = ((const float4*)cw)[e];
        u16x8 taps[11];                               // sliding window rows rb2*8-3 .. rb2*8+7
#pragma unroll
        for (int j = 0; j < 11; ++j) {
            const int tloc = ch * 64 + rb2 * 8 - 3 + j;
            if (tloc >= 0) taps[j] = *(const u16x8*)&P[((long)bb * 1024 + tloc) * N1P + colbase];
            else           taps[j] = u16x8{};
        }
#pragma unroll
        for (int r = 0; r < 8; ++r) {
            float y[8];
            float ss = 0.f;
#pragma unroll
            for (int e = 0; e < 8; ++e) {
                float v = bf2f(taps[r][e]) * wgt[e].x + bf2f(taps[r + 1][e]) * wgt[e].y +
                          bf2f(taps[r + 2][e]) * wgt[e].z + bf2f(taps[r + 3][e]) * wgt[e].w;
                v = v * sigm(v);
                y[e] = v;
                ss += v * v;
            }
            ss += __shfl_xor(ss, 1); ss += __shfl_xor(ss, 2); ss += __shfl_xor(ss, 4);
            const float rn = rsqrtf(ss + 1e-6f);
            const float sc = (g < 8) ? rn * 0.125f : (g < 16 ? rn : 1.f);
            u16x8 o;
#pragma unroll
            for (int e = 0; e < 8; ++e) o[e] = f2bf(y[e] * sc);
            const int row = rb2 * 8 + r;
            if (g < 16) {
                u16* dst = (g < 8) ? Ql : Kl;
                *(u16x8*)((char*)dst + row * 128 + (((g & 7) ^ (row & 7)) << 4)) = o;
            } else {
                *(u16x8*)&Vtmp[row * 128 + (g - 16) * 8] = o;
            }
        }
    }
    __syncthreads();

    // ---- phase 1: cumsum + exp tables (wave 0); VTb build from Vtmp; QK^T / KK^T
    if (wave == 0) {
        float g = gcs[lane];
#pragma unroll
        for (int off = 1; off < 64; off <<= 1) {
            float n = __shfl_up(g, off, 64);
            if (lane >= off) g += n;
        }
        gcs[lane] = g;
        const float gC = __shfl(g, 63);
        const float eg = __expf(g);
        egcs[lane] = eg;
        egcsC[lane] = __expf(gC - g);
        bkc[lane] = betal[lane] * eg;
    }
    for (int u = tid; u < 1024; u += 256) {          // VTb[dv][c] = beta_c * V[c][dv]
        int r = u >> 4, c8 = u & 15;
        u16x8 vv = *(const u16x8*)&Vtmp[r * 128 + c8 * 8];
        float bsc = betal[r];
#pragma unroll
        for (int j = 0; j < 8; ++j) {
            int dv = c8 * 8 + j;
            *(u16*)((char*)VTb + swz64(dv, r)) = f2bf(bf2f(vv[j]) * bsc);
        }
    }
    f32x4 aQK[4] = {}, aKK[4] = {};
#pragma unroll
    for (int nt = 0; nt < 4; ++nt)
#pragma unroll
        for (int kk = 0; kk < 2; ++kk) {
            bf16x8 bq = frag64(Kl, nt * 16, lane, kk);
            aQK[nt] = __builtin_amdgcn_mfma_f32_16x16x32_bf16(frag64(Ql, wave * 16, lane, kk), bq, aQK[nt], 0, 0, 0);
            aKK[nt] = __builtin_amdgcn_mfma_f32_16x16x32_bf16(frag64(Kl, wave * 16, lane, kk), bq, aKK[nt], 0, 0, 0);
        }
    __syncthreads();   // gcs/exp tables + VTb published; Vtmp dead -> Mim/MTim writable

    // ---- phase 2a: CHM, M0 images (MT vectorized), Qc, KT1b, KcT(LDS)
    float am[4][4];
#pragma unroll
    for (int nt = 0; nt < 4; ++nt) {
        const int i = nt * 16 + (lane & 15);
        u16x4 mtv;
#pragma unroll
        for (int reg = 0; reg < 4; ++reg) {
            const int t = tbase + reg;
            const float dec = __expf(gcs[t] - gcs[i]);
            const float mv = (i <= t) ? dec * aQK[nt][reg] : 0.f;
            *(u16*)((char*)CHM + (size_t)bhc * 8192 + swz64(t, i)) = f2bf(mv);
            const float a = (i < t) ? betal[t] * dec * aKK[nt][reg] : 0.f;
            am[nt][reg] = -a;
            const u16 amb = f2bf(-a);
            *(u16*)((char*)Mim + swz64(t, i)) = amb;
            mtv[reg] = amb;
        }
        *(u16x4*)((char*)MTim + i * 128 + ((((tbase >> 3) ^ (i & 7)) << 4) + (tbase & 7) * 2)) = mtv;
    }
    for (int e = tid; e < 4096; e += 256) {
        const int r = e >> 6, c = e & 63;
        const int ib = swz64(r, c);
        const float qv = bf2f(*(const u16*)((const char*)Ql + ib)) * egcs[r];
        *(u16*)((char*)CHQc + (size_t)bhc * 8192 + ib) = f2bf(qv);
        const float kv = bf2f(*(const u16*)((const char*)Kl + ib));
        const int ob = swz64(c, r);
        *(u16*)((char*)KT1b + ob) = f2bf(kv * bkc[r]);
        *(u16*)((char*)KcTl + ob) = f2bf(kv * egcsC[r]);
    }
    if (tid == 0) CHcC[bhc] = egcs[63];
    __syncthreads();   // Ql/Kl dead; Tl overlay becomes safe

    // ---- phase 2b: T0 = I - A (fp32 master + bf16 image, own rows)
#pragma unroll
    for (int nt = 0; nt < 4; ++nt)
#pragma unroll
        for (int reg = 0; reg < 4; ++reg) {
            const int t = tbase + reg;
            const int i = nt * 16 + (lane & 15);
            const float tv = (t == i) ? 1.f : am[nt][reg];
            Tl[t * 64 + i] = tv;
            *(u16*)((char*)Tb + swz64(t, i)) = f2bf(tv);
        }
    __syncthreads();

    // ---- phase 3: doubling. stage j: M <- M^2 (in place), then T <- T + T*M.
    const int hi = wave * 16 + 15;
#pragma unroll
    for (int j = 1; j <= 5; ++j) {
        f32x4 aM[4] = {};
#pragma unroll
        for (int nt = 0; nt < 4; ++nt) {
            if (nt * 16 > hi - (1 << j)) continue;
#pragma unroll
            for (int kk = 0; kk < 2; ++kk) {
                if (kk * 32 > hi) break;
                aM[nt] = __builtin_amdgcn_mfma_f32_16x16x32_bf16(
                    frag64(Mim, wave * 16, lane, kk), frag64(MTim, nt * 16, lane, kk), aM[nt], 0, 0, 0);
            }
        }
        __syncthreads();
#pragma unroll
        for (int nt = 0; nt < 4; ++nt) {
            const int i = nt * 16 + (lane & 15);
            u16x4 mtv;
#pragma unroll
            for (int reg = 0; reg < 4; ++reg) {
                const int t = tbase + reg;
                const float mv = (t - i >= (1 << j)) ? aM[nt][reg] : 0.f;
                const u16 mb = f2bf(mv);
                *(u16*)((char*)Mim + swz64(t, i)) = mb;
                mtv[reg] = mb;
            }
            *(u16x4*)((char*)MTim + i * 128 + ((((tbase >> 3) ^ (i & 7)) << 4) + (tbase & 7) * 2)) = mtv;
        }
        __syncthreads();
        f32x4 aT[4];
#pragma unroll
        for (int nt = 0; nt < 4; ++nt)
#pragma unroll
            for (int reg = 0; reg < 4; ++reg)
                aT[nt][reg] = Tl[(tbase + reg) * 64 + nt * 16 + (lane & 15)];
#pragma unroll
        for (int nt = 0; nt < 4; ++nt) {
            if (nt * 16 > hi - (1 << j)) continue;
#pragma unroll
            for (int kk = 0; kk < 2; ++kk) {
                if (kk * 32 > hi) break;
                aT[nt] = __builtin_amdgcn_mfma_f32_16x16x32_bf16(
                    frag64(Tb, wave * 16, lane, kk), frag64(MTim, nt * 16, lane, kk), aT[nt], 0, 0, 0);
            }
        }
#pragma unroll
        for (int nt = 0; nt < 4; ++nt)
#pragma unroll
            for (int reg = 0; reg < 4; ++reg) {
                const int t = tbase + reg;
                const int i = nt * 16 + (lane & 15);
                Tl[t * 64 + i] = aT[nt][reg];
                *(u16*)((char*)Tb + swz64(t, i)) = f2bf(aT[nt][reg]);
            }
    }
    __syncthreads();   // doubling done; Tb final; Kl/Mim/MTim reusable

    u16* WTl  = Kl;
    u16* U0Tl = Mim;   // 16KB spans Mim+MTim

    // W = T @ (beta*c*K); write CHW + local W^T image
    {
        f32x4 aW[4] = {};
#pragma unroll
        for (int nt = 0; nt < 4; ++nt)
#pragma unroll
            for (int kk = 0; kk < 2; ++kk) {
                if (kk * 32 > hi) break;
                aW[nt] = __builtin_amdgcn_mfma_f32_16x16x32_bf16(
                    frag64(Tb, wave * 16, lane, kk), frag64(KT1b, nt * 16, lane, kk), aW[nt], 0, 0, 0);
            }
#pragma unroll
        for (int nt = 0; nt < 4; ++nt) {
            const int c = nt * 16 + (lane & 15);
            u16x4 wtv;
#pragma unroll
            for (int reg = 0; reg < 4; ++reg) {
                const int r = tbase + reg;
                const u16 wv = f2bf(aW[nt][reg]);
                *(u16*)((char*)CHW + (size_t)bhc * 8192 + swz64(r, c)) = wv;
                wtv[reg] = wv;
            }
            *(u16x4*)((char*)WTl + c * 128 + ((((tbase >> 3) ^ (c & 7)) << 4) + (tbase & 7) * 2)) = wtv;
        }
    }
    // U0T = (beta*V)^T @ T^T; write CHU0T + local image
#pragma unroll
    for (int rt = 0; rt < 2; ++rt) {
        f32x4 aU[4] = {};
        const int rb = (wave * 2 + rt) * 16;
#pragma unroll
        for (int nt = 0; nt < 4; ++nt)
#pragma unroll
            for (int kk = 0; kk < 2; ++kk) {
                if (kk * 32 > nt * 16 + 15) continue;
                aU[nt] = __builtin_amdgcn_mfma_f32_16x16x32_bf16(
                    frag64(VTb, rb, lane, kk), frag64(Tb, nt * 16, lane, kk), aU[nt], 0, 0, 0);
            }
#pragma unroll
        for (int nt = 0; nt < 4; ++nt)
#pragma unroll
            for (int reg = 0; reg < 4; ++reg) {
                const int dv = rb + ((lane >> 4) << 2) + reg;
                const int c = nt * 16 + (lane & 15);
                const u16 uv = f2bf(aU[nt][reg]);
                *(u16*)((char*)CHU0T + (size_t)bhc * 16384 + swz64(dv, c)) = uv;
                *(u16*)((char*)U0Tl + swz64(dv, c)) = uv;
            }
    }
    __syncthreads();   // WTl/U0Tl ready (KcTl was ready since phase 2a)

    // A2m = -(W^T · Kc^T): out [k][dk], store transposed+negated at [dk][k] (vectorized)
    {
        f32x4 aA[4] = {};
#pragma unroll
        for (int nt = 0; nt < 4; ++nt)
#pragma unroll
            for (int kk = 0; kk < 2; ++kk)
                aA[nt] = __builtin_amdgcn_mfma_f32_16x16x32_bf16(
                    frag64(WTl, wave * 16, lane, kk), frag64(KcTl, nt * 16, lane, kk), aA[nt], 0, 0, 0);
#pragma unroll
        for (int nt = 0; nt < 4; ++nt) {
            const int dk = nt * 16 + (lane & 15);
            u16x4 av;
#pragma unroll
            for (int reg = 0; reg < 4; ++reg) av[reg] = f2bf(-aA[nt][reg]);
            *(u16x4*)((char*)CHA2m + (size_t)bhc * 8192 + dk * 128 +
                      ((((tbase >> 3) ^ (dk & 7)) << 4) + (tbase & 7) * 2)) = av;
        }
    }
    // B = U0T · Kc^T: out [dv][dk]
#pragma unroll
    for (int rt = 0; rt < 2; ++rt) {
        f32x4 aB[4] = {};
        const int rb = (wave * 2 + rt) * 16;
#pragma unroll
        for (int nt = 0; nt < 4; ++nt)
#pragma unroll
            for (int kk = 0; kk < 2; ++kk)
                aB[nt] = __builtin_amdgcn_mfma_f32_16x16x32_bf16(
                    frag64(U0Tl, rb, lane, kk), frag64(KcTl, nt * 16, lane, kk), aB[nt], 0, 0, 0);
#pragma unroll
        for (int nt = 0; nt < 4; ++nt)
#pragma unroll
            for (int reg = 0; reg < 4; ++reg) {
                const int dv = rb + ((lane >> 4) << 2) + reg;
                const int dk = nt * 16 + (lane & 15);
                *(u16*)((char*)CHB + (size_t)bhc * 16384 + swz64(dv, dk)) = f2bf(aB[nt][reg]);
            }
    }
}

// ---------------- scan stage 2: minimal sequential recurrence S' = cC*S + S*A2m + B; exports S0
__global__ __launch_bounds__(256) void k_scan2(
    const u16* __restrict__ CHA2m, const u16* __restrict__ CHB,
    const float* __restrict__ CHcC, u16* __restrict__ CHS0) {
    __shared__ __align__(16) u16 stg[2][8192];   // per buf: A2m 8KB | B(dvh) 8KB
    __shared__ __align__(16) u16 STb[4096];
    __shared__ float ST[64 * 66];
    const int blk = blockIdx.x;
    const int bb = blk >> 5, h = (blk >> 1) & 15, dvh = blk & 1;
    const int bh = bb * 16 + h;
    const int tid = threadIdx.x, lane = tid & 63, wave = tid >> 6;

    for (int e = tid; e < 64 * 66; e += 256) ST[e] = 0.f;
    for (int e = tid; e < 4096; e += 256) STb[e] = 0;

    auto stage = [&](int buf, int ch) {
        const size_t base = (size_t)(bh * 16 + ch);
        const u16* sA = CHA2m + base * 4096;
        const u16* sB = CHB + base * 8192 + dvh * 4096;
#pragma unroll
        for (int r = 0; r < 2; ++r) {
            const int g = r * 256 + tid;
            async16(sA + (size_t)g * 8, &stg[buf][g * 8]);
            async16(sB + (size_t)g * 8, &stg[buf][4096 + g * 8]);
        }
    };
    stage(0, 0);
    int cur = 0;
    for (int ch = 0; ch < 16; ++ch) {
        asm volatile("s_waitcnt vmcnt(0)" ::: "memory");
        __syncthreads();
        if (ch < 15) stage(cur ^ 1, ch + 1);
        const u16* sA2 = &stg[cur][0];
        const u16* sB = &stg[cur][4096];
        f32x4 acc[4] = {};
#pragma unroll
        for (int nt = 0; nt < 4; ++nt)
#pragma unroll
            for (int kk = 0; kk < 2; ++kk)
                acc[nt] = __builtin_amdgcn_mfma_f32_16x16x32_bf16(
                    frag64(STb, wave * 16, lane, kk), frag64(sA2, nt * 16, lane, kk), acc[nt], 0, 0, 0);
        const float cC = CHcC[bh * 16 + ch];
        const size_t sbase = ((size_t)(bh * 16 + ch + 1) * 2 + dvh) * 8192;
#pragma unroll
        for (int nt = 0; nt < 4; ++nt)
#pragma unroll
            for (int reg = 0; reg < 4; ++reg) {
                const int rr = wave * 16 + ((lane >> 4) << 2) + reg;
                const int cc = nt * 16 + (lane & 15);
                const float bv = bf2f(*(const u16*)((const char*)sB + swz64(rr, cc)));
                const float ns = cC * ST[rr * 66 + cc] + acc[nt][reg] + bv;
                ST[rr * 66 + cc] = ns;
                const u16 nb = f2bf(ns);
                *(u16*)((char*)STb + swz64(rr, cc)) = nb;
                if (ch < 15) *(u16*)((char*)CHS0 + sbase + swz64(rr, cc)) = nb;
            }
        cur ^= 1;
    }
}

// ---------------- scan stage 3 (fully parallel): u = U0T - S0*W^T; O = M@u + Qc@S0;
// fused per-head RMSNorm * gate -> OG
__global__ __launch_bounds__(256) void k_scan3(
    const u16* __restrict__ CHM, const u16* __restrict__ CHQc, const u16* __restrict__ CHW,
    const u16* __restrict__ CHU0T, const u16* __restrict__ CHS0, const u16* __restrict__ P,
    const float* __restrict__ onw, u16* __restrict__ OG) {
    __shared__ __align__(16) char sm3[73728];
    u16* sM  = (u16*)sm3;                 // 8KB
    u16* sQc = (u16*)(sm3 + 8192);        // 8KB
    u16* sW  = (u16*)(sm3 + 16384);       // 8KB
    u16* sU  = (u16*)(sm3 + 24576);       // 16KB U0T -> u (in place)
    u16* sS0 = (u16*)(sm3 + 40960);       // 16KB
    u16* sPg = (u16*)(sm3 + 57344);       // 16KB gate tile [64][128]
    const int blk = blockIdx.x;           // bb*256 + h*16 + ch
    const int bb = blk >> 8, h = (blk >> 4) & 15, ch = blk & 15;
    const size_t bhc = blk;
    const int tid = threadIdx.x, lane = tid & 63, wave = tid >> 6;
    const bool hasS0 = (ch != 0);

#pragma unroll
    for (int r = 0; r < 2; ++r) {
        const int g = r * 256 + tid;
        async16(CHM + bhc * 4096 + (size_t)g * 8, sM + g * 8);
        async16(CHQc + bhc * 4096 + (size_t)g * 8, sQc + g * 8);
        async16(CHW + bhc * 4096 + (size_t)g * 8, sW + g * 8);
#pragma unroll
        for (int d = 0; d < 2; ++d) {
            async16(CHU0T + (bhc * 2 + d) * 4096 + (size_t)g * 8, sU + d * 4096 + g * 8);
            if (hasS0)
                async16(CHS0 + (bhc * 2 + d) * 4096 + (size_t)g * 8, sS0 + d * 4096 + g * 8);
        }
    }
    const long prow0 = ((long)bb * 1024 + ch * 64) * N1P + 4128 + h * 128;
#pragma unroll
    for (int k = 0; k < 4; ++k) {
        const int i = tid + k * 256;
        const int row = i >> 4, seg = i & 15;
        async16(P + prow0 + (long)row * N1P + seg * 8, sPg + i * 8);
    }
    asm volatile("s_waitcnt vmcnt(0)" ::: "memory");
    __syncthreads();

    if (hasS0) {
        // u = U0T - S0 * W^T (in place, own rows)
#pragma unroll
        for (int d = 0; d < 2; ++d) {
            f32x4 au[4] = {};
#pragma unroll
            for (int nt = 0; nt < 4; ++nt)
#pragma unroll
                for (int kk = 0; kk < 2; ++kk)
                    au[nt] = __builtin_amdgcn_mfma_f32_16x16x32_bf16(
                        frag64(sS0 + d * 4096, wave * 16, lane, kk), frag64(sW, nt * 16, lane, kk),
                        au[nt], 0, 0, 0);
#pragma unroll
            for (int nt = 0; nt < 4; ++nt)
#pragma unroll
                for (int reg = 0; reg < 4; ++reg) {
                    const int dv = wave * 16 + ((lane >> 4) << 2) + reg;
                    const int c = nt * 16 + (lane & 15);
                    u16* p = (u16*)((char*)sU + d * 8192 + swz64(dv, c));
                    *p = f2bf(bf2f(*p) - au[nt][reg]);
                }
        }
        __syncthreads();
    }

    f32x4 accO[2][4] = {};
#pragma unroll
    for (int d = 0; d < 2; ++d)
#pragma unroll
        for (int nt = 0; nt < 4; ++nt)
#pragma unroll
            for (int kk = 0; kk < 2; ++kk) {
                accO[d][nt] = __builtin_amdgcn_mfma_f32_16x16x32_bf16(
                    frag64(sM, wave * 16, lane, kk), frag64(sU + d * 4096, nt * 16, lane, kk),
                    accO[d][nt], 0, 0, 0);
                if (hasS0)
                    accO[d][nt] = __builtin_amdgcn_mfma_f32_16x16x32_bf16(
                        frag64(sQc, wave * 16, lane, kk), frag64(sS0 + d * 4096, nt * 16, lane, kk),
                        accO[d][nt], 0, 0, 0);
            }

    const int rsub = (lane >> 4) * 4, csub = lane & 15;
    float rn[4];
#pragma unroll
    for (int reg = 0; reg < 4; ++reg) {
        float ss = 0.f;
#pragma unroll
        for (int d = 0; d < 2; ++d)
#pragma unroll
            for (int nt = 0; nt < 4; ++nt) {
                const float v = accO[d][nt][reg];
                ss += v * v;
            }
        ss += __shfl_xor(ss, 1); ss += __shfl_xor(ss, 2);
        ss += __shfl_xor(ss, 4); ss += __shfl_xor(ss, 8);
        rn[reg] = rsqrtf(ss * (1.f / 128.f) + 1e-6f);
    }
    __syncthreads();   // done reading sM/sQc/sW/sU/sS0 -> reuse as out tile
    u16* ct = (u16*)sm3;   // [64][136]
#pragma unroll
    for (int d = 0; d < 2; ++d)
#pragma unroll
        for (int nt = 0; nt < 4; ++nt)
#pragma unroll
            for (int reg = 0; reg < 4; ++reg) {
                const int rr = wave * 16 + rsub + reg;
                const int dv = d * 64 + nt * 16 + csub;
                const float g = bf2f(sPg[rr * 128 + dv]);
                const float val = accO[d][nt][reg] * rn[reg] * onw[dv] * g * sigm(g);
                ct[rr * 136 + dv] = f2bf(val);
            }
    __syncthreads();
#pragma unroll
    for (int k = 0; k < 4; ++k) {
        const int f = (tid + k * 256) * 8;
        const int r2 = f >> 7, c = f & 127;
        *(u16x8*)&OG[(size_t)(bb * 1024 + ch * 64 + r2) * 2048 + h * 128 + c] =
            *(const u16x8*)&ct[r2 * 136 + c];
    }
}

extern "C" void kernel_launch(void* const* d_in, const int* in_sizes, int n_in,
                              void* d_out, int out_size, void* d_ws, size_t ws_size,
                              hipStream_t stream) {
    const float* x   = (const float*)d_in[0];
    const float* n1w = (const float*)d_in[1];
    const float* wq  = (const float*)d_in[2];
    const float* wk  = (const float*)d_in[3];
    const float* wv  = (const float*)d_in[4];
    const float* cq  = (const float*)d_in[5];
    const float* ck  = (const float*)d_in[6];
    const float* cv  = (const float*)d_in[7];
    const float* wb  = (const float*)d_in[8];
    const float* wa  = (const float*)d_in[9];
    const float* Alg = (const float*)d_in[10];
    const float* dtb = (const float*)d_in[11];
    const float* wg  = (const float*)d_in[12];
    const float* onw = (const float*)d_in[13];
    const float* wo  = (const float*)d_in[14];
    const float* n2w = (const float*)d_in[15];
    const float* w1  = (const float*)d_in[16];
    const float* w2  = (const float*)d_in[17];
    const float* w3  = (const float*)d_in[18];

    if (ws_size < 132384768ULL) return;

    char* ws = (char*)d_ws;
    u16*   WcatT = (u16*)(ws + 0);            // [6400][1024] bf16 (CHW/CHM/CHQc reuse)
    u16*   WoT   = (u16*)(ws + 13107200);     // [1024][2048]
    u16*   W13T  = (u16*)(ws + 17301504);     // [5632][1024] group-16 interleaved w1/w3
    u16*   W2T   = (u16*)(ws + 28835840);     // [1024][2816]
    u16*   hA    = (u16*)(ws + 34603008);     // [2048][1024] (h2A reuse)
    u16*   P     = (u16*)(ws + 38797312);     // [2048][6400]
    u16*   Mm    = (u16*)(ws + 65011712);     // [2048][2816] bf16 MLP intermediate
    u16*   OG    = (u16*)(ws + 73400320);     // [2048][2048] bf16
    float* X2    = (float*)(ws + 82051072);   // [2048][1024] fp32
    u16*   CHU0T = (u16*)(ws + 103022592);    // [512][128][64] bf16 image
    float* CHcC  = (float*)(ws + 111411200);  // [512]
    u16*   CHA2m = (u16*)(ws + 111413248);    // [512][64][64] bf16 image (-W^T Kc^T, transposed)
    u16*   CHB   = (u16*)(ws + 115607552);    // [512][128][64] bf16 image (U0T Kc^T)
    u16*   CHS0  = (u16*)(ws + 123996160);    // [512*2][64][64] bf16 image per dvh
    u16*   CHW   = WcatT;                     // [512][64][64] image
    u16*   CHM   = (u16*)(ws + 4194304);
    u16*   CHQc  = (u16*)(ws + 8388608);
    u16*   h2A = hA;

    // fused weight transposes (fp32 [K][N] -> bf16 [N][K]) + rmsnorm-1; tiles 64k x 32n
    TJobs tj;
    tj.j[0] = { wq, WcatT, 1024, 1024,    0, 1, 1024,     0, 32, 0 };   // 512
    tj.j[1] = { wk, WcatT, 1024, 1024, 1024, 1, 1024,   512, 32, 0 };   // 512
    tj.j[2] = { wv, WcatT, 1024, 2048, 2048, 1, 2048,  1024, 64, 0 };   // 1024
    tj.j[3] = { wb, WcatT, 1024,   16, 4096, 1,   16,  2048,  1, 0 };   // 16
    tj.j[4] = { wa, WcatT, 1024,   16, 4112, 1,   16,  2064,  1, 0 };   // 16
    tj.j[5] = { wg, WcatT, 1024, 2048, 4128, 1, 2272,  2080, 71, 0 };   // 1136 (pads rows to 6400)
    tj.j[6] = { wo, WoT,   2048, 1024,    0, 1, 1024,  3216, 32, 0 };   // 1024
    tj.j[7] = { w1, W13T,  1024, 2816,    0, 1, 2816,  4240, 88, 1 };   // 1408 group-16 even
    tj.j[8] = { w3, W13T,  1024, 2816,   16, 1, 2816,  5648, 88, 1 };   // 1408 group-16 odd
    tj.j[9] = { w2, W2T,   2816, 1024,    0, 1, 1024,  7056, 32, 0 };   // 1408 -> blkBase end 8464
    k_transpose_all<<<8464 + 2048, 256, 0, stream>>>(tj, 10, 8464, x, n1w, hA);

    k_gemm256<2><<<200, 512, 0, stream>>>(hA, WcatT, P, N1P, 1024);

    k_scan1<<<512, 256, 0, stream>>>(P, cq, ck, cv, Alg, dtb, CHW, CHM, CHQc, CHU0T,
                                     CHcC, CHA2m, CHB);
    k_scan2<<<64, 256, 0, stream>>>(CHA2m, CHB, CHcC, CHS0);
    k_scan3<<<512, 256, 0, stream>>>(CHM, CHQc, CHW, CHU0T, CHS0, P, onw, OG);

    k_gemm_skinny<<<512, 256, 0, stream>>>(OG, WoT, X2, x, 1024, 2048);

    k_rmsnorm<<<2048, 256, 0, stream>>>(X2, n2w, h2A);
    k_gemm256<3><<<176, 512, 0, stream>>>(h2A, W13T, Mm, 2816, 1024);  // fused silu(u1)*u3
    k_gemm_skinny<<<512, 256, 0, stream>>>(Mm, W2T, (float*)d_out, X2, 1024, 2816);
}